// Round 3
// baseline (6344.860 us; speedup 1.0000x reference)
//
#include <hip/hip_runtime.h>
#include <math.h>

#define HH 56
#define WW 56
#define CC 64
#define BB 4
#define HWA (HH*WW)   // 3136

// ---------- 1. NCHW -> NHWC transpose (x) ----------
__global__ void k_transpose(const float* __restrict__ src, float* __restrict__ dst) {
    __shared__ float tile[64][65];
    int blk = blockIdx.x;              // BB * (HWA/64)
    int b   = blk / (HWA/64);
    int t0  = (blk % (HWA/64)) * 64;
    int tid = threadIdx.x;             // 256
    int p   = tid & 63;
    int q   = tid >> 6;                // 0..3
#pragma unroll
    for (int i = 0; i < 16; ++i) {
        int c = q + 4*i;
        tile[p][c] = src[(b*CC + c)*HWA + t0 + p];   // coalesced over p
    }
    __syncthreads();
    int c2 = tid & 63;
#pragma unroll
    for (int i = 0; i < 16; ++i) {
        int p2 = q + 4*i;
        dst[(b*HWA + t0 + p2)*CC + c2] = tile[p2][c2];  // coalesced over c2
    }
}

// ---------- 2. weight transpose OIHW -> [g][ky][ic][kx][GOCpad] ----------
__global__ void k_wtrans(const float* __restrict__ w, float* __restrict__ wt,
                         int OC, int GOCpad) {
    int i = blockIdx.x*256 + threadIdx.x;
    int n = OC*288;
    if (i >= n) return;
    int kx = i % 3;
    int ky = (i/3) % 3;
    int ic = (i/9) & 31;
    int oc = i / 288;
    int half = OC >> 1;
    int g  = (oc >= half) ? 1 : 0;
    int wi = oc - g*half;
    wt[(((g*3 + ky)*32 + ic)*3 + kx)*GOCpad + wi] = w[i];
}

// ---------- 3. merged grouped 3x3 convs: one block per (b,row) ----------
// patch LDS layout: [3 rows][16 ic4][60 cols][4 icin], col = x+1
__global__ __launch_bounds__(256)
void k_conv_both(const float* __restrict__ x,
                 const float* __restrict__ wt3, const float* __restrict__ b3,
                 const float* __restrict__ wt2, const float* __restrict__ b2,
                 float* __restrict__ off3, float* __restrict__ off2) {
    __shared__ float patch[3*16*60*4];   // 46080 B
    int blk = blockIdx.x;                // BB*56
    int b   = blk / 56;
    int h   = blk % 56;
    int tid = threadIdx.x + threadIdx.y*64;   // 256
    int lane = threadIdx.x;              // 0..63
    int y4   = threadIdx.y;              // wave id 0..3

    // zero fill (covers halo cols + OOB rows)
    for (int i = tid; i < 3*16*60*4; i += 256) patch[i] = 0.f;
    __syncthreads();
    // interior fill from NCHW x
    for (int i = tid; i < 3*64*56; i += 256) {
        int xc = i % 56;
        int c  = (i / 56) & 63;
        int r  = i / (56*64);
        int yy = h - 1 + r;
        if (yy >= 0 && yy < HH) {
            float v = x[(b*CC + c)*HWA + yy*WW + xc];
            patch[((r*16 + (c>>2))*60 + xc + 1)*4 + (c&3)] = v;
        }
    }
    __syncthreads();

    int ln = (lane < 56) ? lane : 0;     // clamp idle lanes, keep LDS in-bounds
    const float4* pbase = (const float4*)patch;

    // 22 oc-chunks of 8: ids 0..13 -> conv3 (GOCpad 56, half 49),
    //                    ids 14..21 -> conv2 (GOCpad 32, half 25)
    for (int id = y4; id < 22; id += 4) {
        int idu = __builtin_amdgcn_readfirstlane(id);
        int is3   = (idu < 14);
        int lid   = is3 ? idu : idu - 14;
        int g     = is3 ? (lid / 7) : (lid / 4);
        int ow0   = is3 ? ((lid % 7) * 8) : ((lid % 4) * 8);
        int gpad  = is3 ? 56 : 32;
        int ohalf = is3 ? 49 : 25;
        const float* wp = is3 ? wt3 : wt2;
        const float* bp = is3 ? b3  : b2;
        float*       op = is3 ? off3 : off2;

        const float* wb = wp + (size_t)g*288*gpad + ow0;  // (g,ky=0,ic=0,kx=0,ow0)

        float acc[8];
#pragma unroll
        for (int o = 0; o < 8; ++o)
            acc[o] = (ow0 + o < ohalf) ? bp[g*ohalf + ow0 + o] : 0.f;

#pragma unroll
        for (int ky = 0; ky < 3; ++ky) {
#pragma unroll
            for (int ic4 = 0; ic4 < 8; ++ic4) {
                const float4* prow = pbase + (ky*16 + g*8 + ic4)*60;
                float4 v0 = prow[ln];
                float4 v1 = prow[ln + 1];
                float4 v2 = prow[ln + 2];
                int k0 = (ky*32 + ic4*4)*3;   // weight k index base
#pragma unroll
                for (int icin = 0; icin < 4; ++icin) {
                    float pv0 = (&v0.x)[icin];
                    float pv1 = (&v1.x)[icin];
                    float pv2 = (&v2.x)[icin];
                    const float* w0 = wb + (size_t)(k0 + icin*3 + 0)*gpad;
                    const float* w1 = wb + (size_t)(k0 + icin*3 + 1)*gpad;
                    const float* w2 = wb + (size_t)(k0 + icin*3 + 2)*gpad;
#pragma unroll
                    for (int o = 0; o < 8; ++o) {
                        acc[o] += w0[o]*pv0;
                        acc[o] += w1[o]*pv1;
                        acc[o] += w2[o]*pv2;
                    }
                }
            }
        }
        if (lane < 56) {
#pragma unroll
            for (int o = 0; o < 8; ++o) {
                int wi = ow0 + o;
                if (wi < ohalf) {
                    int ocg = g*ohalf + wi;
                    op[((size_t)(b*2*ohalf + ocg))*HWA + h*WW + lane] = acc[o];
                }
            }
        }
    }
}

// ---------- 4. deformable depthwise conv, NHWC in/out ----------
template<int K, int KS, int PAD>
__global__ void k_deform(const float* __restrict__ src, const float* __restrict__ off,
                         const float* __restrict__ wg, const float* __restrict__ bias,
                         float* __restrict__ out) {
    __shared__ float lw[K*64];         // [t][c], conflict-free lane reads
    int tid = threadIdx.x + threadIdx.y*64;   // 256
    for (int i = tid; i < K*64; i += 256) {
        int c = i / K, t = i % K;
        lw[t*64 + c] = wg[i];
    }
    __syncthreads();

    int blk = blockIdx.x;              // BB * (HWA/4)
    int b   = blk / (HWA/4);
    int hw  = (blk % (HWA/4))*4 + threadIdx.y;
    int h   = hw / WW, w = hw % WW;
    int c   = threadIdx.x;

    const float* offb = off + (size_t)(b*2*K)*HWA + hw;
    const float* srcb = src + (size_t)b*HWA*CC + c;

    float acc = 0.f;
    for (int t = 0; t < K; ++t) {
        int ky = t / KS, kx = t % KS;
        float oy = offb[(2*t  )*HWA];  // wave-broadcast
        float ox = offb[(2*t+1)*HWA];
        float py = (float)(h - PAD + 3*ky) + oy;
        float px = (float)(w - PAD + 3*kx) + ox;
        float y0f = floorf(py), x0f = floorf(px);
        float ly = py - y0f, lx = px - x0f;
        float hy = 1.f - ly, hx = 1.f - lx;
        int y0 = (int)y0f, x0 = (int)x0f;
        bool yi0 = (y0   >= 0) && (y0   < HH);
        bool yi1 = (y0+1 >= 0) && (y0+1 < HH);
        bool xi0 = (x0   >= 0) && (x0   < WW);
        bool xi1 = (x0+1 >= 0) && (x0+1 < WW);
        float v00 = 0.f, v01 = 0.f, v10 = 0.f, v11 = 0.f;
        int base = (y0*WW + x0)*CC;
        if (yi0 && xi0) v00 = srcb[base];
        if (yi0 && xi1) v01 = srcb[base + CC];
        if (yi1 && xi0) v10 = srcb[base + WW*CC];
        if (yi1 && xi1) v11 = srcb[base + WW*CC + CC];
        float val = hy*(hx*v00 + lx*v01) + ly*(hx*v10 + lx*v11);
        acc += val * lw[t*64 + c];
    }
    out[((size_t)b*HWA + hw)*CC + c] = acc + bias[c];
}

// ---------- 5a. GAP stage 1: partial sums over 64-pixel chunks ----------
__global__ void k_gap1(const float* __restrict__ o1, const float* __restrict__ o2,
                       float* __restrict__ partial) {
    __shared__ float red[4][64];
    int blk   = blockIdx.x;            // BB*2*49
    int chunk = blk % 49;
    int f     = (blk / 49) & 1;
    int b     = blk / 98;
    const float* src = f ? o2 : o1;
    int tid = threadIdx.x;             // 256
    int c = tid & 63, s = tid >> 6;
    int hw0 = chunk * 64;
    float sum = 0.f;
#pragma unroll
    for (int i = 0; i < 16; ++i) {
        int hw = hw0 + s + 4*i;
        sum += src[((size_t)b*HWA + hw)*CC + c];   // coalesced 256B per wave
    }
    red[s][c] = sum;
    __syncthreads();
    if (s == 0)
        partial[((size_t)(b*2 + f)*49 + chunk)*64 + c]
            = red[0][c] + red[1][c] + red[2][c] + red[3][c];
}

// ---------- 5b. GAP stage 2: reduce 49 chunks ----------
__global__ void k_gap2(const float* __restrict__ partial, float* __restrict__ gap) {
    int bf = blockIdx.x;               // 8
    int c  = threadIdx.x;              // 64
    const float* p = partial + (size_t)bf*49*64 + c;
    float tot = 0.f;
    for (int j = 0; j < 49; ++j) tot += p[j*64];
    gap[bf*64 + c] = tot * (1.f/HWA);
}

// ---------- 6. softmax gate + combine, NHWC -> NCHW ----------
__global__ void k_combine(const float* __restrict__ o1, const float* __restrict__ o2,
                          const float* __restrict__ gap, float* __restrict__ out) {
    __shared__ float tile[64][65];
    int blk = blockIdx.x;              // BB * (HWA/64)
    int b   = blk / (HWA/64);
    int t0  = (blk % (HWA/64)) * 64;
    int tid = threadIdx.x;             // 256
    int c = tid & 63, q = tid >> 6;

    float g1 = gap[(b*2+0)*CC + c];
    float g2 = gap[(b*2+1)*CC + c];
    float m  = fmaxf(g1, g2);
    float e1 = expf(g1 - m), e2 = expf(g2 - m);
    float a1 = e1 / (e1 + e2), a2 = 1.f - a1;

#pragma unroll
    for (int i = 0; i < 16; ++i) {
        int p = q + 4*i;
        size_t idx = ((size_t)b*HWA + t0 + p)*CC + c;
        tile[p][c] = o1[idx]*a1 + o2[idx]*a2;
    }
    __syncthreads();
    int p2 = tid & 63;
#pragma unroll
    for (int i = 0; i < 16; ++i) {
        int c2 = q + 4*i;
        out[((size_t)b*CC + c2)*HWA + t0 + p2] = tile[p2][c2];
    }
}

extern "C" void kernel_launch(void* const* d_in, const int* in_sizes, int n_in,
                              void* d_out, int out_size, void* d_ws, size_t ws_size,
                              hipStream_t stream) {
    const float* x      = (const float*)d_in[0];
    const float* w_off3 = (const float*)d_in[1];
    const float* b_off3 = (const float*)d_in[2];
    const float* w_off2 = (const float*)d_in[3];
    const float* b_off2 = (const float*)d_in[4];
    const float* w7     = (const float*)d_in[5];
    const float* b7     = (const float*)d_in[6];
    const float* w5     = (const float*)d_in[7];
    const float* b5     = (const float*)d_in[8];
    float* out = (float*)d_out;

    float* ws   = (float*)d_ws;
    float* x_t  = ws;                     // 802816
    float* off3 = x_t  + 802816;          // 1229312
    float* off2 = off3 + 1229312;         // 627200
    float* out1 = off2 + 627200;          // 802816
    float* out2 = out1 + 802816;          // 802816
    float* gap  = out2 + 802816;          // 512
    float* wt3  = gap  + 512;             // 576*56 = 32256
    float* wt2  = wt3  + 32256;           // 576*32 = 18432
    float* gpart= wt2  + 18432;           // 8*49*64 = 25088
    size_t need = (size_t)(802816*3 + 1229312 + 627200 + 512 + 32256 + 18432 + 25088) * 4;
    if (ws_size < need) return;           // fail loudly via wrong output

    // x -> NHWC (feeds deform1 only; conv reads NCHW x directly)
    k_transpose<<<BB*(HWA/64), 256, 0, stream>>>(x, x_t);
    // weight transposes
    k_wtrans<<<(98*288 + 255)/256, 256, 0, stream>>>(w_off3, wt3, 98, 56);
    k_wtrans<<<(50*288 + 255)/256, 256, 0, stream>>>(w_off2, wt2, 50, 32);
    // merged offset convs
    k_conv_both<<<BB*56, dim3(64,4), 0, stream>>>(x, wt3, b_off3, wt2, b_off2, off3, off2);
    // deform 1: k=7, pad=9, dil=3, src = x_t
    k_deform<49,7,9><<<BB*(HWA/4), dim3(64,4), 0, stream>>>(x_t, off3, w7, b7, out1);
    // deform 2: k=5, pad=6, dil=3, src = out1
    k_deform<25,5,6><<<BB*(HWA/4), dim3(64,4), 0, stream>>>(out1, off2, w5, b5, out2);
    // gate (two-stage deterministic reduction)
    k_gap1<<<BB*2*49, 256, 0, stream>>>(out1, out2, gpart);
    k_gap2<<<BB*2, 64, 0, stream>>>(gpart, gap);
    k_combine<<<BB*(HWA/64), 256, 0, stream>>>(out1, out2, gap, out);
}

// Round 4
// 361.389 us; speedup vs baseline: 17.5569x; 17.5569x over previous
//
#include <hip/hip_runtime.h>
#include <math.h>

#define HH 56
#define WW 56
#define CC 64
#define BB 4
#define HWA (HH*WW)   // 3136
#define NCHUNK 22
#define WTCH 2304     // per-chunk packed weights: 3ky * 32ic * 3kx * 8(ocpad)

// ---------- 1. NCHW -> NHWC transpose (x) ----------
__global__ void k_transpose(const float* __restrict__ src, float* __restrict__ dst) {
    __shared__ float tile[64][65];
    int blk = blockIdx.x;              // BB * (HWA/64)
    int b   = blk / (HWA/64);
    int t0  = (blk % (HWA/64)) * 64;
    int tid = threadIdx.x;             // 256
    int p   = tid & 63;
    int q   = tid >> 6;                // 0..3
#pragma unroll
    for (int i = 0; i < 16; ++i) {
        int c = q + 4*i;
        tile[p][c] = src[(b*CC + c)*HWA + t0 + p];
    }
    __syncthreads();
    int c2 = tid & 63;
#pragma unroll
    for (int i = 0; i < 16; ++i) {
        int p2 = q + 4*i;
        dst[(b*HWA + t0 + p2)*CC + c2] = tile[p2][c2];
    }
}

// ---------- 2. pack weights+bias into per-chunk layout ----------
// chunk 0..13: conv3 (g=lid/7, ow0=(lid%7)*7, ohalf=49)
// chunk 14..21: conv2 (g=lid/4, ow0=(lid%4)*7, ohalf=25)
// wt layout: [chunk][ky][ic][kx][8], zero-padded; bp: [chunk][8]
__global__ void k_wpack(const float* __restrict__ w3, const float* __restrict__ b3,
                        const float* __restrict__ w2, const float* __restrict__ b2,
                        float* __restrict__ wt, float* __restrict__ bp) {
    int i = blockIdx.x*256 + threadIdx.x;
    if (i < NCHUNK*WTCH) {
        int chunk = i / WTCH, r = i % WTCH;
        int o8 = r & 7;
        int kx = (r >> 3) % 3;
        int ic = (r / 24) & 31;
        int ky = r / 768;
        int is3 = chunk < 14;
        int lid = is3 ? chunk : chunk - 14;
        int g   = is3 ? lid/7 : lid/4;
        int ow0 = is3 ? (lid%7)*7 : (lid%4)*7;
        int ohalf = is3 ? 49 : 25;
        const float* w = is3 ? w3 : w2;
        int ol = ow0 + o8;
        float v = 0.f;
        if (o8 < 7 && ol < ohalf)
            v = w[(g*ohalf + ol)*288 + ic*9 + ky*3 + kx];
        wt[i] = v;
    } else {
        int j = i - NCHUNK*WTCH;
        if (j < NCHUNK*8) {
            int chunk = j >> 3, o8 = j & 7;
            int is3 = chunk < 14;
            int lid = is3 ? chunk : chunk - 14;
            int g   = is3 ? lid/7 : lid/4;
            int ow0 = is3 ? (lid%7)*7 : (lid%4)*7;
            int ohalf = is3 ? 49 : 25;
            const float* bb = is3 ? b3 : b2;
            int ol = ow0 + o8;
            float v = 0.f;
            if (o8 < 7 && ol < ohalf) v = bb[g*ohalf + ol];
            bp[j] = v;
        }
    }
}

// ---------- 3. grouped 3x3 convs: block = (b, chunk, 8-row band) ----------
// weights are block-uniform -> SGPR s_loads; input band staged in LDS.
__global__ __launch_bounds__(128)
void k_conv(const float* __restrict__ x, const float* __restrict__ wt,
            const float* __restrict__ bp,
            float* __restrict__ off3, float* __restrict__ off2) {
    __shared__ float patch[10*32*58];   // 74240 B: rows band0-1..band0+8
    int blk   = blockIdx.x;             // BB*22*7
    int chunk = blk % 22;
    int band  = (blk / 22) % 7;
    int b     = blk / 154;
    int is3   = chunk < 14;
    int lid   = is3 ? chunk : chunk - 14;
    int g     = is3 ? lid/7 : lid/4;
    int ow0   = is3 ? (lid%7)*7 : (lid%4)*7;
    int ohalf = is3 ? 49 : 25;
    float* op = is3 ? off3 : off2;
    int band0 = band * 8;

    int tid = threadIdx.x;              // 128
    const float* xs = x + ((size_t)b*CC + g*32)*HWA;
    for (int i = tid; i < 10*32*58; i += 128) {
        int col = i % 58;
        int ic  = (i / 58) & 31;
        int r   = i / (58*32);
        int y   = band0 - 1 + r;
        int xc  = col - 1;
        float v = 0.f;
        if (y >= 0 && y < HH && xc >= 0 && xc < WW)
            v = xs[ic*HWA + y*WW + xc];
        patch[i] = v;
    }
    __syncthreads();

    int wv   = tid >> 6;                // wave 0..1 -> rows wv*4..wv*4+3
    int lane = tid & 63;
    int ln   = (lane < 56) ? lane : 55; // clamp idle lanes

    const float* wtc = wt + chunk*WTCH;
    const float* bpc = bp + chunk*8;
    float acc[4][7];
#pragma unroll
    for (int r = 0; r < 4; ++r)
#pragma unroll
        for (int o = 0; o < 7; ++o) acc[r][o] = bpc[o];

#pragma unroll 1
    for (int ky = 0; ky < 3; ++ky) {
        const float* prow = patch + ((wv*4 + ky)*32)*58 + ln;
        const float* wbb  = wtc + ky*768;
#pragma unroll 2
        for (int ic = 0; ic < 32; ++ic) {
            const float* wb = wbb + ic*24;          // [kx][8], uniform -> s_load
            const float* pr = prow + ic*58;
#pragma unroll
            for (int r = 0; r < 4; ++r) {
                float v0 = pr[r*32*58];
                float v1 = pr[r*32*58 + 1];
                float v2 = pr[r*32*58 + 2];
#pragma unroll
                for (int o = 0; o < 7; ++o)
                    acc[r][o] += wb[o]*v0 + wb[8+o]*v1 + wb[16+o]*v2;
            }
        }
    }

    if (lane < 56) {
#pragma unroll
        for (int r = 0; r < 4; ++r) {
            int y = band0 + wv*4 + r;
#pragma unroll
            for (int o = 0; o < 7; ++o) {
                int ol = ow0 + o;
                if (ol < ohalf)
                    op[((size_t)(b*2*ohalf) + g*ohalf + ol)*HWA + y*WW + lane] = acc[r][o];
            }
        }
    }
}

// ---------- 4. deformable depthwise conv, NHWC in/out ----------
template<int K, int KS, int PAD>
__global__ void k_deform(const float* __restrict__ src, const float* __restrict__ off,
                         const float* __restrict__ wg, const float* __restrict__ bias,
                         float* __restrict__ out) {
    __shared__ float lw[K*64];
    int tid = threadIdx.x + threadIdx.y*64;   // 256
    for (int i = tid; i < K*64; i += 256) {
        int c = i / K, t = i % K;
        lw[t*64 + c] = wg[i];
    }
    __syncthreads();

    int blk = blockIdx.x;              // BB * (HWA/4)
    int b   = blk / (HWA/4);
    int hw  = (blk % (HWA/4))*4 + threadIdx.y;
    int h   = hw / WW, w = hw % WW;
    int c   = threadIdx.x;

    const float* offb = off + (size_t)(b*2*K)*HWA + hw;
    const float* srcb = src + (size_t)b*HWA*CC + c;

    float acc = 0.f;
    for (int t = 0; t < K; ++t) {
        int ky = t / KS, kx = t % KS;
        float oy = offb[(2*t  )*HWA];
        float ox = offb[(2*t+1)*HWA];
        float py = (float)(h - PAD + 3*ky) + oy;
        float px = (float)(w - PAD + 3*kx) + ox;
        float y0f = floorf(py), x0f = floorf(px);
        float ly = py - y0f, lx = px - x0f;
        float hy = 1.f - ly, hx = 1.f - lx;
        int y0 = (int)y0f, x0 = (int)x0f;
        bool yi0 = (y0   >= 0) && (y0   < HH);
        bool yi1 = (y0+1 >= 0) && (y0+1 < HH);
        bool xi0 = (x0   >= 0) && (x0   < WW);
        bool xi1 = (x0+1 >= 0) && (x0+1 < WW);
        float v00 = 0.f, v01 = 0.f, v10 = 0.f, v11 = 0.f;
        int base = (y0*WW + x0)*CC;
        if (yi0 && xi0) v00 = srcb[base];
        if (yi0 && xi1) v01 = srcb[base + CC];
        if (yi1 && xi0) v10 = srcb[base + WW*CC];
        if (yi1 && xi1) v11 = srcb[base + WW*CC + CC];
        float val = hy*(hx*v00 + lx*v01) + ly*(hx*v10 + lx*v11);
        acc += val * lw[t*64 + c];
    }
    out[((size_t)b*HWA + hw)*CC + c] = acc + bias[c];
}

// ---------- 5a. GAP stage 1 ----------
__global__ void k_gap1(const float* __restrict__ o1, const float* __restrict__ o2,
                       float* __restrict__ partial) {
    __shared__ float red[4][64];
    int blk   = blockIdx.x;            // BB*2*49
    int chunk = blk % 49;
    int f     = (blk / 49) & 1;
    int b     = blk / 98;
    const float* src = f ? o2 : o1;
    int tid = threadIdx.x;             // 256
    int c = tid & 63, s = tid >> 6;
    int hw0 = chunk * 64;
    float sum = 0.f;
#pragma unroll
    for (int i = 0; i < 16; ++i) {
        int hw = hw0 + s + 4*i;
        sum += src[((size_t)b*HWA + hw)*CC + c];
    }
    red[s][c] = sum;
    __syncthreads();
    if (s == 0)
        partial[((size_t)(b*2 + f)*49 + chunk)*64 + c]
            = red[0][c] + red[1][c] + red[2][c] + red[3][c];
}

// ---------- 5b. GAP stage 2 ----------
__global__ void k_gap2(const float* __restrict__ partial, float* __restrict__ gap) {
    int bf = blockIdx.x;               // 8
    int c  = threadIdx.x;              // 64
    const float* p = partial + (size_t)bf*49*64 + c;
    float tot = 0.f;
    for (int j = 0; j < 49; ++j) tot += p[j*64];
    gap[bf*64 + c] = tot * (1.f/HWA);
}

// ---------- 6. softmax gate + combine, NHWC -> NCHW ----------
__global__ void k_combine(const float* __restrict__ o1, const float* __restrict__ o2,
                          const float* __restrict__ gap, float* __restrict__ out) {
    __shared__ float tile[64][65];
    int blk = blockIdx.x;              // BB * (HWA/64)
    int b   = blk / (HWA/64);
    int t0  = (blk % (HWA/64)) * 64;
    int tid = threadIdx.x;             // 256
    int c = tid & 63, q = tid >> 6;

    float g1 = gap[(b*2+0)*CC + c];
    float g2 = gap[(b*2+1)*CC + c];
    float m  = fmaxf(g1, g2);
    float e1 = expf(g1 - m), e2 = expf(g2 - m);
    float a1 = e1 / (e1 + e2), a2 = 1.f - a1;

#pragma unroll
    for (int i = 0; i < 16; ++i) {
        int p = q + 4*i;
        size_t idx = ((size_t)b*HWA + t0 + p)*CC + c;
        tile[p][c] = o1[idx]*a1 + o2[idx]*a2;
    }
    __syncthreads();
    int p2 = tid & 63;
#pragma unroll
    for (int i = 0; i < 16; ++i) {
        int c2 = q + 4*i;
        out[((size_t)b*CC + c2)*HWA + t0 + p2] = tile[p2][c2];
    }
}

extern "C" void kernel_launch(void* const* d_in, const int* in_sizes, int n_in,
                              void* d_out, int out_size, void* d_ws, size_t ws_size,
                              hipStream_t stream) {
    const float* x      = (const float*)d_in[0];
    const float* w_off3 = (const float*)d_in[1];
    const float* b_off3 = (const float*)d_in[2];
    const float* w_off2 = (const float*)d_in[3];
    const float* b_off2 = (const float*)d_in[4];
    const float* w7     = (const float*)d_in[5];
    const float* b7     = (const float*)d_in[6];
    const float* w5     = (const float*)d_in[7];
    const float* b5     = (const float*)d_in[8];
    float* out = (float*)d_out;

    float* ws   = (float*)d_ws;
    float* x_t  = ws;                     // 802816 (also reused as gpart later)
    float* off3 = x_t  + 802816;          // 1229312
    float* off2 = off3 + 1229312;         // 627200
    float* out1 = off2 + 627200;          // 802816
    float* out2 = out1 + 802816;          // 802816
    float* gap  = out2 + 802816;          // 512
    float* wtb  = gap  + 512;             // 22*2304 = 50688
    float* bpb  = wtb  + 50688;           // 22*8 = 176
    float* gpart = x_t;                   // alias: x_t is dead after deform1
    size_t need = (size_t)(802816*3 + 1229312 + 627200 + 512 + 50688 + 176) * 4;
    if (ws_size < need) return;

    // x -> NHWC (feeds deform1; conv reads NCHW x directly)
    k_transpose<<<BB*(HWA/64), 256, 0, stream>>>(x, x_t);
    // pack weights + bias per chunk
    k_wpack<<<(NCHUNK*WTCH + NCHUNK*8 + 255)/256, 256, 0, stream>>>(
        w_off3, b_off3, w_off2, b_off2, wtb, bpb);
    // both grouped convs
    k_conv<<<BB*22*7, 128, 0, stream>>>(x, wtb, bpb, off3, off2);
    // deform 1: k=7, pad=9, dil=3, src = x_t
    k_deform<49,7,9><<<BB*(HWA/4), dim3(64,4), 0, stream>>>(x_t, off3, w7, b7, out1);
    // deform 2: k=5, pad=6, dil=3, src = out1
    k_deform<25,5,6><<<BB*(HWA/4), dim3(64,4), 0, stream>>>(out1, off2, w5, b5, out2);
    // gate
    k_gap1<<<BB*2*49, 256, 0, stream>>>(out1, out2, gpart);
    k_gap2<<<BB*2, 64, 0, stream>>>(gpart, gap);
    k_combine<<<BB*(HWA/64), 256, 0, stream>>>(out1, out2, gap, out);
}

// Round 5
// 360.341 us; speedup vs baseline: 17.6079x; 1.0029x over previous
//
#include <hip/hip_runtime.h>
#include <math.h>

#define HH 56
#define WW 56
#define CC 64
#define BB 4
#define HWA (HH*WW)   // 3136
#define NCHUNK 22
#define WTCH 2304     // per-chunk packed weights: 3ky * 32ic * 3kx * 8(ocpad)

// ---------- 1. NCHW -> NHWC transpose (x) ----------
__global__ void k_transpose(const float* __restrict__ src, float* __restrict__ dst) {
    __shared__ float tile[64][65];
    int blk = blockIdx.x;              // BB * (HWA/64)
    int b   = blk / (HWA/64);
    int t0  = (blk % (HWA/64)) * 64;
    int tid = threadIdx.x;             // 256
    int p   = tid & 63;
    int q   = tid >> 6;                // 0..3
#pragma unroll
    for (int i = 0; i < 16; ++i) {
        int c = q + 4*i;
        tile[p][c] = src[(b*CC + c)*HWA + t0 + p];
    }
    __syncthreads();
    int c2 = tid & 63;
#pragma unroll
    for (int i = 0; i < 16; ++i) {
        int p2 = q + 4*i;
        dst[(b*HWA + t0 + p2)*CC + c2] = tile[p2][c2];
    }
}

// ---------- 2. pack weights+bias into per-chunk layout ----------
// chunk 0..13: conv3 (g=lid/7, ow0=(lid%7)*7, ohalf=49)
// chunk 14..21: conv2 (g=lid/4, ow0=(lid%4)*7, ohalf=25)
// wt layout: [chunk][ky][ic][kx][8], zero-padded; bp: [chunk][8]
__global__ void k_wpack(const float* __restrict__ w3, const float* __restrict__ b3,
                        const float* __restrict__ w2, const float* __restrict__ b2,
                        float* __restrict__ wt, float* __restrict__ bp) {
    int i = blockIdx.x*256 + threadIdx.x;
    if (i < NCHUNK*WTCH) {
        int chunk = i / WTCH, r = i % WTCH;
        int o8 = r & 7;
        int kx = (r >> 3) % 3;
        int ic = (r / 24) & 31;
        int ky = r / 768;
        int is3 = chunk < 14;
        int lid = is3 ? chunk : chunk - 14;
        int g   = is3 ? lid/7 : lid/4;
        int ow0 = is3 ? (lid%7)*7 : (lid%4)*7;
        int ohalf = is3 ? 49 : 25;
        const float* w = is3 ? w3 : w2;
        int ol = ow0 + o8;
        float v = 0.f;
        if (o8 < 7 && ol < ohalf)
            v = w[(g*ohalf + ol)*288 + ic*9 + ky*3 + kx];
        wt[i] = v;
    } else {
        int j = i - NCHUNK*WTCH;
        if (j < NCHUNK*8) {
            int chunk = j >> 3, o8 = j & 7;
            int is3 = chunk < 14;
            int lid = is3 ? chunk : chunk - 14;
            int g   = is3 ? lid/7 : lid/4;
            int ow0 = is3 ? (lid%7)*7 : (lid%4)*7;
            int ohalf = is3 ? 49 : 25;
            const float* bb = is3 ? b3 : b2;
            int ol = ow0 + o8;
            float v = 0.f;
            if (o8 < 7 && ol < ohalf) v = bb[g*ohalf + ol];
            bp[j] = v;
        }
    }
}

// ---------- 3. grouped 3x3 convs: block = (b, 4-row band, chunk) ----------
// 4 waves, one output row each. Weights are block-uniform -> SGPR s_loads.
__global__ __launch_bounds__(256)
void k_conv(const float* __restrict__ x, const float* __restrict__ wt,
            const float* __restrict__ bp,
            float* __restrict__ off3, float* __restrict__ off2) {
    __shared__ float patch[6*32*58];    // 44544 B: rows band0-1..band0+4
    int blk   = blockIdx.x;             // BB*14*22
    int chunk = blk % 22;
    int band  = (blk / 22) % 14;
    int b     = blk / 308;
    int is3   = chunk < 14;
    int lid   = is3 ? chunk : chunk - 14;
    int g     = is3 ? lid/7 : lid/4;
    int ow0   = is3 ? (lid%7)*7 : (lid%4)*7;
    int ohalf = is3 ? 49 : 25;
    float* op = is3 ? off3 : off2;
    int band0 = band * 4;

    int tid = threadIdx.x;              // 256
    const float* xs = x + ((size_t)b*CC + g*32)*HWA;
    for (int i = tid; i < 6*32*58; i += 256) {
        int col = i % 58;
        int ic  = (i / 58) & 31;
        int r   = i / (58*32);
        int y   = band0 - 1 + r;
        int xc  = col - 1;
        float v = 0.f;
        if (y >= 0 && y < HH && xc >= 0 && xc < WW)
            v = xs[ic*HWA + y*WW + xc];
        patch[i] = v;
    }
    __syncthreads();

    int wv   = tid >> 6;                // wave 0..3 -> output row band0+wv
    int lane = tid & 63;
    int ln   = (lane < 56) ? lane : 55; // clamp idle lanes

    const float* wtc = wt + chunk*WTCH;
    const float* bpc = bp + chunk*8;
    float acc[7];
#pragma unroll
    for (int o = 0; o < 7; ++o) acc[o] = bpc[o];

#pragma unroll 1
    for (int ky = 0; ky < 3; ++ky) {
        const float* prow = patch + ((wv + ky)*32)*58 + ln;
        const float* wbb  = wtc + ky*768;
#pragma unroll 4
        for (int ic = 0; ic < 32; ++ic) {
            const float* wb = wbb + ic*24;          // [kx][8], uniform -> s_load
            const float* pr = prow + ic*58;
            float v0 = pr[0];
            float v1 = pr[1];
            float v2 = pr[2];
#pragma unroll
            for (int o = 0; o < 7; ++o)
                acc[o] += wb[o]*v0 + wb[8+o]*v1 + wb[16+o]*v2;
        }
    }

    if (lane < 56) {
        int y = band0 + wv;
#pragma unroll
        for (int o = 0; o < 7; ++o) {
            int ol = ow0 + o;
            if (ol < ohalf)
                op[((size_t)(b*2*ohalf) + g*ohalf + ol)*HWA + y*WW + lane] = acc[o];
        }
    }
}

// ---------- 4. deformable depthwise conv, NHWC in/out ----------
// offsets for the block's 4 pixels staged in LDS (one pipelined pass),
// so the tap loop reads them as free wave-broadcast LDS loads.
template<int K, int KS, int PAD>
__global__ void k_deform(const float* __restrict__ src, const float* __restrict__ off,
                         const float* __restrict__ wg, const float* __restrict__ bias,
                         float* __restrict__ out) {
    __shared__ float lw[K*64];          // [t][c]
    __shared__ float loff[2*K*4];       // [2K rows][4 px]
    int tid = threadIdx.x + threadIdx.y*64;   // 256
    int blk = blockIdx.x;               // BB * (HWA/4)
    int b   = blk / (HWA/4);
    int hw0 = (blk % (HWA/4))*4;

    for (int i = tid; i < K*64; i += 256) {
        int c = i / K, t = i % K;
        lw[t*64 + c] = wg[i];
    }
    for (int i = tid; i < 8*K; i += 256) {
        int row = i >> 2, p = i & 3;
        loff[i] = off[((size_t)b*2*K + row)*HWA + hw0 + p];
    }
    __syncthreads();

    int yp = threadIdx.y;               // 0..3
    int hw = hw0 + yp;
    int h  = hw / WW, w = hw % WW;
    int c  = threadIdx.x;

    const float* srcb = src + (size_t)b*HWA*CC + c;

    float acc = 0.f;
    for (int t = 0; t < K; ++t) {
        int ky = t / KS, kx = t % KS;
        float oy = loff[8*t + yp];          // wave-broadcast LDS read
        float ox = loff[8*t + 4 + yp];
        float py = (float)(h - PAD + 3*ky) + oy;
        float px = (float)(w - PAD + 3*kx) + ox;
        float y0f = floorf(py), x0f = floorf(px);
        float ly = py - y0f, lx = px - x0f;
        float hy = 1.f - ly, hx = 1.f - lx;
        int y0 = (int)y0f, x0 = (int)x0f;
        bool yi0 = (y0   >= 0) && (y0   < HH);
        bool yi1 = (y0+1 >= 0) && (y0+1 < HH);
        bool xi0 = (x0   >= 0) && (x0   < WW);
        bool xi1 = (x0+1 >= 0) && (x0+1 < WW);
        float v00 = 0.f, v01 = 0.f, v10 = 0.f, v11 = 0.f;
        int base = (y0*WW + x0)*CC;
        if (yi0 && xi0) v00 = srcb[base];
        if (yi0 && xi1) v01 = srcb[base + CC];
        if (yi1 && xi0) v10 = srcb[base + WW*CC];
        if (yi1 && xi1) v11 = srcb[base + WW*CC + CC];
        float val = hy*(hx*v00 + lx*v01) + ly*(hx*v10 + lx*v11);
        acc += val * lw[t*64 + c];
    }
    out[((size_t)b*HWA + hw)*CC + c] = acc + bias[c];
}

// ---------- 5a. GAP stage 1 ----------
__global__ void k_gap1(const float* __restrict__ o1, const float* __restrict__ o2,
                       float* __restrict__ partial) {
    __shared__ float red[4][64];
    int blk   = blockIdx.x;            // BB*2*49
    int chunk = blk % 49;
    int f     = (blk / 49) & 1;
    int b     = blk / 98;
    const float* src = f ? o2 : o1;
    int tid = threadIdx.x;             // 256
    int c = tid & 63, s = tid >> 6;
    int hw0 = chunk * 64;
    float sum = 0.f;
#pragma unroll
    for (int i = 0; i < 16; ++i) {
        int hw = hw0 + s + 4*i;
        sum += src[((size_t)b*HWA + hw)*CC + c];
    }
    red[s][c] = sum;
    __syncthreads();
    if (s == 0)
        partial[((size_t)(b*2 + f)*49 + chunk)*64 + c]
            = red[0][c] + red[1][c] + red[2][c] + red[3][c];
}

// ---------- 5b. GAP stage 2 ----------
__global__ void k_gap2(const float* __restrict__ partial, float* __restrict__ gap) {
    int bf = blockIdx.x;               // 8
    int c  = threadIdx.x;              // 64
    const float* p = partial + (size_t)bf*49*64 + c;
    float tot = 0.f;
    for (int j = 0; j < 49; ++j) tot += p[j*64];
    gap[bf*64 + c] = tot * (1.f/HWA);
}

// ---------- 6. softmax gate + combine, NHWC -> NCHW ----------
__global__ void k_combine(const float* __restrict__ o1, const float* __restrict__ o2,
                          const float* __restrict__ gap, float* __restrict__ out) {
    __shared__ float tile[64][65];
    int blk = blockIdx.x;              // BB * (HWA/64)
    int b   = blk / (HWA/64);
    int t0  = (blk % (HWA/64)) * 64;
    int tid = threadIdx.x;             // 256
    int c = tid & 63, q = tid >> 6;

    float g1 = gap[(b*2+0)*CC + c];
    float g2 = gap[(b*2+1)*CC + c];
    float m  = fmaxf(g1, g2);
    float e1 = expf(g1 - m), e2 = expf(g2 - m);
    float a1 = e1 / (e1 + e2), a2 = 1.f - a1;

#pragma unroll
    for (int i = 0; i < 16; ++i) {
        int p = q + 4*i;
        size_t idx = ((size_t)b*HWA + t0 + p)*CC + c;
        tile[p][c] = o1[idx]*a1 + o2[idx]*a2;
    }
    __syncthreads();
    int p2 = tid & 63;
#pragma unroll
    for (int i = 0; i < 16; ++i) {
        int c2 = q + 4*i;
        out[((size_t)b*CC + c2)*HWA + t0 + p2] = tile[p2][c2];
    }
}

extern "C" void kernel_launch(void* const* d_in, const int* in_sizes, int n_in,
                              void* d_out, int out_size, void* d_ws, size_t ws_size,
                              hipStream_t stream) {
    const float* x      = (const float*)d_in[0];
    const float* w_off3 = (const float*)d_in[1];
    const float* b_off3 = (const float*)d_in[2];
    const float* w_off2 = (const float*)d_in[3];
    const float* b_off2 = (const float*)d_in[4];
    const float* w7     = (const float*)d_in[5];
    const float* b7     = (const float*)d_in[6];
    const float* w5     = (const float*)d_in[7];
    const float* b5     = (const float*)d_in[8];
    float* out = (float*)d_out;

    float* ws   = (float*)d_ws;
    float* x_t  = ws;                     // 802816 (reused as gpart later)
    float* off3 = x_t  + 802816;          // 1229312
    float* off2 = off3 + 1229312;         // 627200
    float* out1 = off2 + 627200;          // 802816
    float* out2 = out1 + 802816;          // 802816
    float* gap  = out2 + 802816;          // 512
    float* wtb  = gap  + 512;             // 22*2304 = 50688
    float* bpb  = wtb  + 50688;           // 22*8 = 176
    float* gpart = x_t;                   // alias: x_t is dead after deform1
    size_t need = (size_t)(802816*3 + 1229312 + 627200 + 512 + 50688 + 176) * 4;
    if (ws_size < need) return;

    // x -> NHWC (feeds deform1; conv reads NCHW x directly)
    k_transpose<<<BB*(HWA/64), 256, 0, stream>>>(x, x_t);
    // pack weights + bias per chunk
    k_wpack<<<(NCHUNK*WTCH + NCHUNK*8 + 255)/256, 256, 0, stream>>>(
        w_off3, b_off3, w_off2, b_off2, wtb, bpb);
    // both grouped convs
    k_conv<<<BB*14*22, 256, 0, stream>>>(x, wtb, bpb, off3, off2);
    // deform 1: k=7, pad=9, dil=3, src = x_t
    k_deform<49,7,9><<<BB*(HWA/4), dim3(64,4), 0, stream>>>(x_t, off3, w7, b7, out1);
    // deform 2: k=5, pad=6, dil=3, src = out1
    k_deform<25,5,6><<<BB*(HWA/4), dim3(64,4), 0, stream>>>(out1, off2, w5, b5, out2);
    // gate
    k_gap1<<<BB*2*49, 256, 0, stream>>>(out1, out2, gpart);
    k_gap2<<<BB*2, 64, 0, stream>>>(gpart, gap);
    k_combine<<<BB*(HWA/64), 256, 0, stream>>>(out1, out2, gap, out);
}

// Round 6
// 341.576 us; speedup vs baseline: 18.5752x; 1.0549x over previous
//
#include <hip/hip_runtime.h>
#include <math.h>

#define HH 56
#define WW 56
#define CC 64
#define BB 4
#define HWA (HH*WW)   // 3136
#define NCHUNK 22
#define WTCH 2304     // per-chunk packed weights: 3ky * 32ic * 3kx * 8(ocpad)

// ---------- 1. NCHW -> NHWC transpose (x) ----------
__global__ void k_transpose(const float* __restrict__ src, float* __restrict__ dst) {
    __shared__ float tile[64][65];
    int blk = blockIdx.x;              // BB * (HWA/64)
    int b   = blk / (HWA/64);
    int t0  = (blk % (HWA/64)) * 64;
    int tid = threadIdx.x;             // 256
    int p   = tid & 63;
    int q   = tid >> 6;                // 0..3
#pragma unroll
    for (int i = 0; i < 16; ++i) {
        int c = q + 4*i;
        tile[p][c] = src[(b*CC + c)*HWA + t0 + p];
    }
    __syncthreads();
    int c2 = tid & 63;
#pragma unroll
    for (int i = 0; i < 16; ++i) {
        int p2 = q + 4*i;
        dst[(b*HWA + t0 + p2)*CC + c2] = tile[p2][c2];
    }
}

// ---------- 2. pack weights+bias into per-chunk layout ----------
__global__ void k_wpack(const float* __restrict__ w3, const float* __restrict__ b3,
                        const float* __restrict__ w2, const float* __restrict__ b2,
                        float* __restrict__ wt, float* __restrict__ bp) {
    int i = blockIdx.x*256 + threadIdx.x;
    if (i < NCHUNK*WTCH) {
        int chunk = i / WTCH, r = i % WTCH;
        int o8 = r & 7;
        int kx = (r >> 3) % 3;
        int ic = (r / 24) & 31;
        int ky = r / 768;
        int is3 = chunk < 14;
        int lid = is3 ? chunk : chunk - 14;
        int g   = is3 ? lid/7 : lid/4;
        int ow0 = is3 ? (lid%7)*7 : (lid%4)*7;
        int ohalf = is3 ? 49 : 25;
        const float* w = is3 ? w3 : w2;
        int ol = ow0 + o8;
        float v = 0.f;
        if (o8 < 7 && ol < ohalf)
            v = w[(g*ohalf + ol)*288 + ic*9 + ky*3 + kx];
        wt[i] = v;
    } else {
        int j = i - NCHUNK*WTCH;
        if (j < NCHUNK*8) {
            int chunk = j >> 3, o8 = j & 7;
            int is3 = chunk < 14;
            int lid = is3 ? chunk : chunk - 14;
            int g   = is3 ? lid/7 : lid/4;
            int ow0 = is3 ? (lid%7)*7 : (lid%4)*7;
            int ohalf = is3 ? 49 : 25;
            const float* bb = is3 ? b3 : b2;
            int ol = ow0 + o8;
            float v = 0.f;
            if (o8 < 7 && ol < ohalf) v = bb[g*ohalf + ol];
            bp[j] = v;
        }
    }
}

// ---------- 3. grouped 3x3 convs: block = (b, 4-row band, chunk) ----------
__global__ __launch_bounds__(256)
void k_conv(const float* __restrict__ x, const float* __restrict__ wt,
            const float* __restrict__ bp,
            float* __restrict__ off3, float* __restrict__ off2) {
    __shared__ float patch[6*32*58];    // 44544 B
    int blk   = blockIdx.x;             // BB*14*22
    int chunk = blk % 22;
    int band  = (blk / 22) % 14;
    int b     = blk / 308;
    int is3   = chunk < 14;
    int lid   = is3 ? chunk : chunk - 14;
    int g     = is3 ? lid/7 : lid/4;
    int ow0   = is3 ? (lid%7)*7 : (lid%4)*7;
    int ohalf = is3 ? 49 : 25;
    float* op = is3 ? off3 : off2;
    int band0 = band * 4;

    int tid = threadIdx.x;              // 256
    const float* xs = x + ((size_t)b*CC + g*32)*HWA;
    for (int i = tid; i < 6*32*58; i += 256) {
        int col = i % 58;
        int ic  = (i / 58) & 31;
        int r   = i / (58*32);
        int y   = band0 - 1 + r;
        int xc  = col - 1;
        float v = 0.f;
        if (y >= 0 && y < HH && xc >= 0 && xc < WW)
            v = xs[ic*HWA + y*WW + xc];
        patch[i] = v;
    }
    __syncthreads();

    int wv   = tid >> 6;                // wave 0..3 -> output row band0+wv
    int lane = tid & 63;
    int ln   = (lane < 56) ? lane : 55;

    const float* wtc = wt + chunk*WTCH;
    const float* bpc = bp + chunk*8;
    float acc[7];
#pragma unroll
    for (int o = 0; o < 7; ++o) acc[o] = bpc[o];

#pragma unroll 1
    for (int ky = 0; ky < 3; ++ky) {
        const float* prow = patch + ((wv + ky)*32)*58 + ln;
        const float* wbb  = wtc + ky*768;
#pragma unroll 4
        for (int ic = 0; ic < 32; ++ic) {
            const float* wb = wbb + ic*24;
            const float* pr = prow + ic*58;
            float v0 = pr[0];
            float v1 = pr[1];
            float v2 = pr[2];
#pragma unroll
            for (int o = 0; o < 7; ++o)
                acc[o] += wb[o]*v0 + wb[8+o]*v1 + wb[16+o]*v2;
        }
    }

    if (lane < 56) {
        int y = band0 + wv;
#pragma unroll
        for (int o = 0; o < 7; ++o) {
            int ol = ow0 + o;
            if (ol < ohalf)
                op[((size_t)(b*2*ohalf) + g*ohalf + ol)*HWA + y*WW + lane] = acc[o];
        }
    }
}

// ---------- 4. deformable depthwise conv, NHWC in/out ----------
// Slab-swizzled grid: blk&7 -> (batch, image-half) so each XCD's L2 holds one
// 1.6MB half-image + halo. Offsets staged in LDS; lw padded (stride 65).
template<int K, int KS, int PAD>
__global__ void k_deform(const float* __restrict__ src, const float* __restrict__ off,
                         const float* __restrict__ wg, const float* __restrict__ bias,
                         float* __restrict__ out) {
    __shared__ float lw[K*65];          // [t][c], stride-65: conflict-free staging
    __shared__ float loff[2*K*4];       // [2K rows][4 px]
    int tid = threadIdx.x + threadIdx.y*64;   // 256
    int blk = blockIdx.x;               // BB * (HWA/4) = 3136
    int xcd  = blk & 7;                 // slab id: 4 batches x 2 halves
    int idx  = blk >> 3;                // 0..391 within slab
    int b    = xcd >> 1;
    int hw0  = (xcd & 1)*(HWA/2) + idx*4;

    for (int i = tid; i < K*64; i += 256) {
        int c = i / K, t = i % K;
        lw[t*65 + c] = wg[i];           // write addr stride 65 over lanes
    }
    for (int i = tid; i < 8*K; i += 256) {
        int row = i >> 2, p = i & 3;
        loff[i] = off[((size_t)b*2*K + row)*HWA + hw0 + p];
    }
    __syncthreads();

    int yp = threadIdx.y;               // 0..3
    int hw = hw0 + yp;
    int h  = hw / WW, w = hw % WW;
    int c  = threadIdx.x;

    const float* srcb = src + (size_t)b*HWA*CC + c;

    float acc = 0.f;
    for (int t = 0; t < K; ++t) {
        int ky = t / KS, kx = t % KS;
        float oy = loff[8*t + yp];          // broadcast LDS read
        float ox = loff[8*t + 4 + yp];
        float py = (float)(h - PAD + 3*ky) + oy;
        float px = (float)(w - PAD + 3*kx) + ox;
        float y0f = floorf(py), x0f = floorf(px);
        float ly = py - y0f, lx = px - x0f;
        float hy = 1.f - ly, hx = 1.f - lx;
        int y0 = (int)y0f, x0 = (int)x0f;
        bool yi0 = (y0   >= 0) && (y0   < HH);
        bool yi1 = (y0+1 >= 0) && (y0+1 < HH);
        bool xi0 = (x0   >= 0) && (x0   < WW);
        bool xi1 = (x0+1 >= 0) && (x0+1 < WW);
        float v00 = 0.f, v01 = 0.f, v10 = 0.f, v11 = 0.f;
        int base = (y0*WW + x0)*CC;
        if (yi0 && xi0) v00 = srcb[base];
        if (yi0 && xi1) v01 = srcb[base + CC];
        if (yi1 && xi0) v10 = srcb[base + WW*CC];
        if (yi1 && xi1) v11 = srcb[base + WW*CC + CC];
        float val = hy*(hx*v00 + lx*v01) + ly*(hx*v10 + lx*v11);
        acc += val * lw[t*65 + c];
    }
    out[((size_t)b*HWA + hw)*CC + c] = acc + bias[c];
}

// ---------- 5a. GAP stage 1 ----------
__global__ void k_gap1(const float* __restrict__ o1, const float* __restrict__ o2,
                       float* __restrict__ partial) {
    __shared__ float red[4][64];
    int blk   = blockIdx.x;            // BB*2*49
    int chunk = blk % 49;
    int f     = (blk / 49) & 1;
    int b     = blk / 98;
    const float* src = f ? o2 : o1;
    int tid = threadIdx.x;             // 256
    int c = tid & 63, s = tid >> 6;
    int hw0 = chunk * 64;
    float sum = 0.f;
#pragma unroll
    for (int i = 0; i < 16; ++i) {
        int hw = hw0 + s + 4*i;
        sum += src[((size_t)b*HWA + hw)*CC + c];
    }
    red[s][c] = sum;
    __syncthreads();
    if (s == 0)
        partial[((size_t)(b*2 + f)*49 + chunk)*64 + c]
            = red[0][c] + red[1][c] + red[2][c] + red[3][c];
}

// ---------- 5b. GAP stage 2 ----------
__global__ void k_gap2(const float* __restrict__ partial, float* __restrict__ gap) {
    int bf = blockIdx.x;               // 8
    int c  = threadIdx.x;              // 64
    const float* p = partial + (size_t)bf*49*64 + c;
    float tot = 0.f;
    for (int j = 0; j < 49; ++j) tot += p[j*64];
    gap[bf*64 + c] = tot * (1.f/HWA);
}

// ---------- 6. softmax gate + combine, NHWC -> NCHW ----------
__global__ void k_combine(const float* __restrict__ o1, const float* __restrict__ o2,
                          const float* __restrict__ gap, float* __restrict__ out) {
    __shared__ float tile[64][65];
    int blk = blockIdx.x;              // BB * (HWA/64)
    int b   = blk / (HWA/64);
    int t0  = (blk % (HWA/64)) * 64;
    int tid = threadIdx.x;             // 256
    int c = tid & 63, q = tid >> 6;

    float g1 = gap[(b*2+0)*CC + c];
    float g2 = gap[(b*2+1)*CC + c];
    float m  = fmaxf(g1, g2);
    float e1 = expf(g1 - m), e2 = expf(g2 - m);
    float a1 = e1 / (e1 + e2), a2 = 1.f - a1;

#pragma unroll
    for (int i = 0; i < 16; ++i) {
        int p = q + 4*i;
        size_t idx = ((size_t)b*HWA + t0 + p)*CC + c;
        tile[p][c] = o1[idx]*a1 + o2[idx]*a2;
    }
    __syncthreads();
    int p2 = tid & 63;
#pragma unroll
    for (int i = 0; i < 16; ++i) {
        int c2 = q + 4*i;
        out[((size_t)b*CC + c2)*HWA + t0 + p2] = tile[p2][c2];
    }
}

extern "C" void kernel_launch(void* const* d_in, const int* in_sizes, int n_in,
                              void* d_out, int out_size, void* d_ws, size_t ws_size,
                              hipStream_t stream) {
    const float* x      = (const float*)d_in[0];
    const float* w_off3 = (const float*)d_in[1];
    const float* b_off3 = (const float*)d_in[2];
    const float* w_off2 = (const float*)d_in[3];
    const float* b_off2 = (const float*)d_in[4];
    const float* w7     = (const float*)d_in[5];
    const float* b7     = (const float*)d_in[6];
    const float* w5     = (const float*)d_in[7];
    const float* b5     = (const float*)d_in[8];
    float* out = (float*)d_out;

    float* ws   = (float*)d_ws;
    float* x_t  = ws;                     // 802816 (reused as gpart later)
    float* off3 = x_t  + 802816;          // 1229312
    float* off2 = off3 + 1229312;         // 627200
    float* out1 = off2 + 627200;          // 802816
    float* out2 = out1 + 802816;          // 802816
    float* gap  = out2 + 802816;          // 512
    float* wtb  = gap  + 512;             // 22*2304 = 50688
    float* bpb  = wtb  + 50688;           // 22*8 = 176
    float* gpart = x_t;                   // alias: x_t dead after deform1
    size_t need = (size_t)(802816*3 + 1229312 + 627200 + 512 + 50688 + 176) * 4;
    if (ws_size < need) return;

    k_transpose<<<BB*(HWA/64), 256, 0, stream>>>(x, x_t);
    k_wpack<<<(NCHUNK*WTCH + NCHUNK*8 + 255)/256, 256, 0, stream>>>(
        w_off3, b_off3, w_off2, b_off2, wtb, bpb);
    k_conv<<<BB*14*22, 256, 0, stream>>>(x, wtb, bpb, off3, off2);
    k_deform<49,7,9><<<BB*(HWA/4), dim3(64,4), 0, stream>>>(x_t, off3, w7, b7, out1);
    k_deform<25,5,6><<<BB*(HWA/4), dim3(64,4), 0, stream>>>(out1, off2, w5, b5, out2);
    k_gap1<<<BB*2*49, 256, 0, stream>>>(out1, out2, gpart);
    k_gap2<<<BB*2, 64, 0, stream>>>(gpart, gap);
    k_combine<<<BB*(HWA/64), 256, 0, stream>>>(out1, out2, gap, out);
}

// Round 7
// 266.546 us; speedup vs baseline: 23.8040x; 1.2815x over previous
//
#include <hip/hip_runtime.h>
#include <hip/hip_fp16.h>
#include <math.h>

#define HH 56
#define WW 56
#define CC 64
#define BB 4
#define HWA (HH*WW)   // 3136
#define NCHUNK 22
#define WTCH 2304

// ---------- 1a. x NCHW -> fp16 x-pair layout xp[b][y][j][c] ----------
// slot j in [0,57): {v(y,j-1,c), v(y,j,c)}, OOB-x zeroed.
__global__ void k_pairx(const float* __restrict__ x, __half2* __restrict__ xp) {
    __shared__ float ld[64*57];        // [c][xcol] padded stride 57
    int blk = blockIdx.x;              // BB*56
    int b = blk / 56, y = blk % 56;
    int tid = threadIdx.x;             // 256
    for (int i = tid; i < 64*56; i += 256) {
        int c = i / 56, xcol = i % 56;
        ld[c*57 + xcol] = x[((size_t)b*CC + c)*HWA + y*WW + xcol];
    }
    __syncthreads();
    for (int i = tid; i < 57*64; i += 256) {
        int j = i >> 6, c = i & 63;
        float lo = (j > 0)  ? ld[c*57 + j - 1] : 0.f;
        float hi = (j < 56) ? ld[c*57 + j]     : 0.f;
        xp[((size_t)(b*HH + y)*57 + j)*CC + c] = __floats2half2_rn(lo, hi);
    }
}

// ---------- 1b. out1 NHWC fp32 -> fp16 pair layout ----------
__global__ void k_pairo(const float* __restrict__ o, __half2* __restrict__ xp) {
    __shared__ float ld[56*64];        // [xcol][c]
    int blk = blockIdx.x;              // BB*56
    int b = blk / 56, y = blk % 56;
    int tid = threadIdx.x;             // 256
    for (int i = tid; i < 56*64; i += 256)
        ld[i] = o[((size_t)b*HWA + y*WW)*CC + i];
    __syncthreads();
    for (int i = tid; i < 57*64; i += 256) {
        int j = i >> 6, c = i & 63;
        float lo = (j > 0)  ? ld[(j-1)*64 + c] : 0.f;
        float hi = (j < 56) ? ld[j*64 + c]     : 0.f;
        xp[((size_t)(b*HH + y)*57 + j)*CC + c] = __floats2half2_rn(lo, hi);
    }
}

// ---------- 1c. offset transpose [2K][HWA] -> [HWA][2K] per batch ----------
__global__ void k_offT(const float* __restrict__ off, float* __restrict__ offT, int R) {
    __shared__ float tile[98*65];
    int blk = blockIdx.x;              // BB*49
    int b = blk / 49;
    int hw0 = (blk % 49) * 64;
    int tid = threadIdx.x;             // 256
    for (int i = tid; i < R*64; i += 256) {
        int row = i >> 6, p = i & 63;
        tile[row*65 + p] = off[((size_t)b*R + row)*HWA + hw0 + p];
    }
    __syncthreads();
    for (int i = tid; i < 64*R; i += 256) {
        int p = i / R, t = i % R;
        offT[((size_t)b*HWA + hw0 + p)*R + t] = tile[t*65 + p];
    }
}

// ---------- 2. pack conv weights+bias per chunk ----------
__global__ void k_wpack(const float* __restrict__ w3, const float* __restrict__ b3,
                        const float* __restrict__ w2, const float* __restrict__ b2,
                        float* __restrict__ wt, float* __restrict__ bp) {
    int i = blockIdx.x*256 + threadIdx.x;
    if (i < NCHUNK*WTCH) {
        int chunk = i / WTCH, r = i % WTCH;
        int o8 = r & 7;
        int kx = (r >> 3) % 3;
        int ic = (r / 24) & 31;
        int ky = r / 768;
        int is3 = chunk < 14;
        int lid = is3 ? chunk : chunk - 14;
        int g   = is3 ? lid/7 : lid/4;
        int ow0 = is3 ? (lid%7)*7 : (lid%4)*7;
        int ohalf = is3 ? 49 : 25;
        const float* w = is3 ? w3 : w2;
        int ol = ow0 + o8;
        float v = 0.f;
        if (o8 < 7 && ol < ohalf)
            v = w[(g*ohalf + ol)*288 + ic*9 + ky*3 + kx];
        wt[i] = v;
    } else {
        int j = i - NCHUNK*WTCH;
        if (j < NCHUNK*8) {
            int chunk = j >> 3, o8 = j & 7;
            int is3 = chunk < 14;
            int lid = is3 ? chunk : chunk - 14;
            int g   = is3 ? lid/7 : lid/4;
            int ow0 = is3 ? (lid%7)*7 : (lid%4)*7;
            int ohalf = is3 ? 49 : 25;
            const float* bb = is3 ? b3 : b2;
            int ol = ow0 + o8;
            float v = 0.f;
            if (o8 < 7 && ol < ohalf) v = bb[g*ohalf + ol];
            bp[j] = v;
        }
    }
}

// ---------- 3. grouped 3x3 convs ----------
__global__ __launch_bounds__(256)
void k_conv(const float* __restrict__ x, const float* __restrict__ wt,
            const float* __restrict__ bp,
            float* __restrict__ off3, float* __restrict__ off2) {
    __shared__ float patch[6*32*58];
    int blk   = blockIdx.x;             // BB*14*22
    int chunk = blk % 22;
    int band  = (blk / 22) % 14;
    int b     = blk / 308;
    int is3   = chunk < 14;
    int lid   = is3 ? chunk : chunk - 14;
    int g     = is3 ? lid/7 : lid/4;
    int ow0   = is3 ? (lid%7)*7 : (lid%4)*7;
    int ohalf = is3 ? 49 : 25;
    float* op = is3 ? off3 : off2;
    int band0 = band * 4;

    int tid = threadIdx.x;              // 256
    const float* xs = x + ((size_t)b*CC + g*32)*HWA;
    for (int i = tid; i < 6*32*58; i += 256) {
        int col = i % 58;
        int ic  = (i / 58) & 31;
        int r   = i / (58*32);
        int y   = band0 - 1 + r;
        int xc  = col - 1;
        float v = 0.f;
        if (y >= 0 && y < HH && xc >= 0 && xc < WW)
            v = xs[ic*HWA + y*WW + xc];
        patch[i] = v;
    }
    __syncthreads();

    int wv   = tid >> 6;
    int lane = tid & 63;
    int ln   = (lane < 56) ? lane : 55;

    const float* wtc = wt + chunk*WTCH;
    const float* bpc = bp + chunk*8;
    float acc[7];
#pragma unroll
    for (int o = 0; o < 7; ++o) acc[o] = bpc[o];

#pragma unroll 1
    for (int ky = 0; ky < 3; ++ky) {
        const float* prow = patch + ((wv + ky)*32)*58 + ln;
        const float* wbb  = wtc + ky*768;
#pragma unroll 4
        for (int ic = 0; ic < 32; ++ic) {
            const float* wb = wbb + ic*24;
            const float* pr = prow + ic*58;
            float v0 = pr[0];
            float v1 = pr[1];
            float v2 = pr[2];
#pragma unroll
            for (int o = 0; o < 7; ++o)
                acc[o] += wb[o]*v0 + wb[8+o]*v1 + wb[16+o]*v2;
        }
    }

    if (lane < 56) {
        int y = band0 + wv;
#pragma unroll
        for (int o = 0; o < 7; ++o) {
            int ol = ow0 + o;
            if (ol < ohalf)
                op[((size_t)(b*2*ohalf) + g*ohalf + ol)*HWA + y*WW + lane] = acc[o];
        }
    }
}

// ---------- 4. deformable depthwise conv: fp16-pair src, transposed offsets ----------
template<int K, int KS, int PAD>
__global__ void k_deform(const __half2* __restrict__ xp, const float* __restrict__ offT,
                         const float* __restrict__ wg, const float* __restrict__ bias,
                         float* __restrict__ out) {
    constexpr int R2 = 2*K;
    __shared__ float lw[K*65];          // [t][c] padded
    __shared__ float loff[4*R2];        // [px][2K]
    int tid = threadIdx.x + threadIdx.y*64;   // 256
    int blk = blockIdx.x;               // 3136
    int xcd = blk & 7;                  // slab: (batch, image-half)
    int idx = blk >> 3;
    int b   = xcd >> 1;
    int hw0 = (xcd & 1)*(HWA/2) + idx*4;

    for (int i = tid; i < K*64; i += 256) {
        int c = i / K, t = i % K;
        lw[t*65 + c] = wg[i];
    }
    for (int i = tid; i < 4*R2; i += 256) {
        int p = i / R2, t = i % R2;
        loff[p*R2 + t] = offT[((size_t)b*HWA + hw0 + p)*R2 + t];
    }
    __syncthreads();

    int yp = threadIdx.y;
    int hw = hw0 + yp;
    int h  = hw / WW, w = hw % WW;
    int c  = threadIdx.x;

    const __half2* xb = xp + (size_t)b*HH*57*CC + c;

    float acc = 0.f;
#pragma unroll 2
    for (int t = 0; t < K; ++t) {
        int ky = t / KS, kx = t % KS;
        float oy = loff[yp*R2 + 2*t];       // broadcast LDS
        float ox = loff[yp*R2 + 2*t + 1];
        float py = (float)(h - PAD + 3*ky) + oy;
        float px = (float)(w - PAD + 3*kx) + ox;
        float y0f = floorf(py), x0f = floorf(px);
        float ly = py - y0f, lx = px - x0f;
        float hy = 1.f - ly, hx = 1.f - lx;
        int y0 = (int)y0f, x0 = (int)x0f;
        int j = x0 + 1;                     // pair slot
        float v00 = 0.f, v01 = 0.f, v10 = 0.f, v11 = 0.f;
        if (j >= 0 && j <= 56) {
            if (y0 >= 0 && y0 < HH) {
                float2 r0 = __half22float2(xb[((size_t)y0*57 + j)*CC]);
                v00 = r0.x; v01 = r0.y;
            }
            int y1 = y0 + 1;
            if (y1 >= 0 && y1 < HH) {
                float2 r1 = __half22float2(xb[((size_t)y1*57 + j)*CC]);
                v10 = r1.x; v11 = r1.y;
            }
        }
        acc += (hy*(hx*v00 + lx*v01) + ly*(hx*v10 + lx*v11)) * lw[t*65 + c];
    }
    out[((size_t)b*HWA + hw)*CC + c] = acc + bias[c];
}

// ---------- 5a. GAP stage 1 ----------
__global__ void k_gap1(const float* __restrict__ o1, const float* __restrict__ o2,
                       float* __restrict__ partial) {
    __shared__ float red[4][64];
    int blk   = blockIdx.x;            // BB*2*49
    int chunk = blk % 49;
    int f     = (blk / 49) & 1;
    int b     = blk / 98;
    const float* src = f ? o2 : o1;
    int tid = threadIdx.x;             // 256
    int c = tid & 63, s = tid >> 6;
    int hw0 = chunk * 64;
    float sum = 0.f;
#pragma unroll
    for (int i = 0; i < 16; ++i) {
        int hw = hw0 + s + 4*i;
        sum += src[((size_t)b*HWA + hw)*CC + c];
    }
    red[s][c] = sum;
    __syncthreads();
    if (s == 0)
        partial[((size_t)(b*2 + f)*49 + chunk)*64 + c]
            = red[0][c] + red[1][c] + red[2][c] + red[3][c];
}

// ---------- 5b. GAP stage 2 ----------
__global__ void k_gap2(const float* __restrict__ partial, float* __restrict__ gap) {
    int bf = blockIdx.x;               // 8
    int c  = threadIdx.x;              // 64
    const float* p = partial + (size_t)bf*49*64 + c;
    float tot = 0.f;
    for (int j = 0; j < 49; ++j) tot += p[j*64];
    gap[bf*64 + c] = tot * (1.f/HWA);
}

// ---------- 6. softmax gate + combine, NHWC -> NCHW ----------
__global__ void k_combine(const float* __restrict__ o1, const float* __restrict__ o2,
                          const float* __restrict__ gap, float* __restrict__ out) {
    __shared__ float tile[64][65];
    int blk = blockIdx.x;              // BB * (HWA/64)
    int b   = blk / (HWA/64);
    int t0  = (blk % (HWA/64)) * 64;
    int tid = threadIdx.x;             // 256
    int c = tid & 63, q = tid >> 6;

    float g1 = gap[(b*2+0)*CC + c];
    float g2 = gap[(b*2+1)*CC + c];
    float m  = fmaxf(g1, g2);
    float e1 = expf(g1 - m), e2 = expf(g2 - m);
    float a1 = e1 / (e1 + e2), a2 = 1.f - a1;

#pragma unroll
    for (int i = 0; i < 16; ++i) {
        int p = q + 4*i;
        size_t idx = ((size_t)b*HWA + t0 + p)*CC + c;
        tile[p][c] = o1[idx]*a1 + o2[idx]*a2;
    }
    __syncthreads();
    int p2 = tid & 63;
#pragma unroll
    for (int i = 0; i < 16; ++i) {
        int c2 = q + 4*i;
        out[((size_t)b*CC + c2)*HWA + t0 + p2] = tile[p2][c2];
    }
}

extern "C" void kernel_launch(void* const* d_in, const int* in_sizes, int n_in,
                              void* d_out, int out_size, void* d_ws, size_t ws_size,
                              hipStream_t stream) {
    const float* x      = (const float*)d_in[0];
    const float* w_off3 = (const float*)d_in[1];
    const float* b_off3 = (const float*)d_in[2];
    const float* w_off2 = (const float*)d_in[3];
    const float* b_off2 = (const float*)d_in[4];
    const float* w7     = (const float*)d_in[5];
    const float* b7     = (const float*)d_in[6];
    const float* w5     = (const float*)d_in[7];
    const float* b5     = (const float*)d_in[8];
    float* out = (float*)d_out;

    float* ws    = (float*)d_ws;
    float* off3r = ws;                    // 1229312 (later: xp2 alias)
    float* off2r = off3r + 1229312;       // 627200  (later: gpart alias)
    float* offT3 = off2r + 627200;        // 1229312
    float* offT2 = offT3 + 1229312;       // 627200
    float* out1  = offT2 + 627200;        // 802816
    float* out2  = out1  + 802816;        // 802816
    float* xp1f  = out2  + 802816;        // 817152 (half2 = 4B units)
    float* gapv  = xp1f  + 817152;        // 512
    float* wtb   = gapv  + 512;           // 50688
    float* bpb   = wtb   + 50688;         // 176
    __half2* xp1 = (__half2*)xp1f;
    __half2* xp2 = (__half2*)off3r;       // alias: off3r dead after k_offT
    float* gpart = off2r;                 // alias: off2r dead after k_offT
    size_t need = (size_t)(1229312 + 627200 + 1229312 + 627200 + 802816*2
                           + 817152 + 512 + 50688 + 176) * 4;
    if (ws_size < need) return;

    k_pairx<<<BB*56, 256, 0, stream>>>(x, xp1);
    k_wpack<<<(NCHUNK*WTCH + NCHUNK*8 + 255)/256, 256, 0, stream>>>(
        w_off3, b_off3, w_off2, b_off2, wtb, bpb);
    k_conv<<<BB*14*22, 256, 0, stream>>>(x, wtb, bpb, off3r, off2r);
    k_offT<<<BB*49, 256, 0, stream>>>(off3r, offT3, 98);
    k_offT<<<BB*49, 256, 0, stream>>>(off2r, offT2, 50);
    k_deform<49,7,9><<<BB*(HWA/4), dim3(64,4), 0, stream>>>(xp1, offT3, w7, b7, out1);
    k_pairo<<<BB*56, 256, 0, stream>>>(out1, xp2);
    k_deform<25,5,6><<<BB*(HWA/4), dim3(64,4), 0, stream>>>(xp2, offT2, w5, b5, out2);
    k_gap1<<<BB*2*49, 256, 0, stream>>>(out1, out2, gpart);
    k_gap2<<<BB*2, 64, 0, stream>>>(gpart, gapv);
    k_combine<<<BB*(HWA/64), 256, 0, stream>>>(out1, out2, gapv, out);
}

// Round 8
// 221.639 us; speedup vs baseline: 28.6270x; 1.2026x over previous
//
#include <hip/hip_runtime.h>
#include <hip/hip_fp16.h>
#include <math.h>

#define HH 56
#define WW 56
#define CC 64
#define BB 4
#define HWA (HH*WW)   // 3136

typedef _Float16 half8_t __attribute__((ext_vector_type(8)));
typedef float f32x4_t __attribute__((ext_vector_type(4)));

// ---------- 1a. x NCHW -> fp16 x-pair layout xp[b][y][j][c] (deform1 src) ----------
__global__ void k_pairx(const float* __restrict__ x, __half2* __restrict__ xp) {
    __shared__ float ld[64*57];        // [c][xcol] padded stride 57
    int blk = blockIdx.x;              // BB*56
    int b = blk / 56, y = blk % 56;
    int tid = threadIdx.x;             // 256
    for (int i = tid; i < 64*56; i += 256) {
        int c = i / 56, xcol = i % 56;
        ld[c*57 + xcol] = x[((size_t)b*CC + c)*HWA + y*WW + xcol];
    }
    __syncthreads();
    for (int i = tid; i < 57*64; i += 256) {
        int j = i >> 6, c = i & 63;
        float lo = (j > 0)  ? ld[c*57 + j - 1] : 0.f;
        float hi = (j < 56) ? ld[c*57 + j]     : 0.f;
        xp[((size_t)(b*HH + y)*57 + j)*CC + c] = __floats2half2_rn(lo, hi);
    }
}

// ---------- 1b. out1 NHWC fp32 -> fp16 pair layout (deform2 src) ----------
__global__ void k_pairo(const float* __restrict__ o, __half2* __restrict__ xp) {
    __shared__ float ld[56*64];        // [xcol][c]
    int blk = blockIdx.x;              // BB*56
    int b = blk / 56, y = blk % 56;
    int tid = threadIdx.x;             // 256
    for (int i = tid; i < 56*64; i += 256)
        ld[i] = o[((size_t)b*HWA + y*WW)*CC + i];
    __syncthreads();
    for (int i = tid; i < 57*64; i += 256) {
        int j = i >> 6, c = i & 63;
        float lo = (j > 0)  ? ld[(j-1)*64 + c] : 0.f;
        float hi = (j < 56) ? ld[j*64 + c]     : 0.f;
        xp[((size_t)(b*HH + y)*57 + j)*CC + c] = __floats2half2_rn(lo, hi);
    }
}

// ---------- 1c. offset transpose [2K][HWA] -> [HWA][2K] per batch ----------
__global__ void k_offT(const float* __restrict__ off, float* __restrict__ offT, int R) {
    __shared__ float tile[98*65];
    int blk = blockIdx.x;              // BB*49
    int b = blk / 49;
    int hw0 = (blk % 49) * 64;
    int tid = threadIdx.x;             // 256
    for (int i = tid; i < R*64; i += 256) {
        int row = i >> 6, p = i & 63;
        tile[row*65 + p] = off[((size_t)b*R + row)*HWA + hw0 + p];
    }
    __syncthreads();
    for (int i = tid; i < 64*R; i += 256) {
        int p = i / R, t = i % R;
        offT[((size_t)b*HWA + hw0 + p)*R + t] = tile[t*65 + p];
    }
}

// ---------- 2a. x NCHW -> xh[b][g][y][col 58][ic 32] fp16 (conv B-source) ----------
// col j holds x-column j-1; j=0 and j=57 are zero (left/right halo).
__global__ void k_xh(const float* __restrict__ x, _Float16* __restrict__ xh) {
    __shared__ float ld[32*57];        // [ic][xcol] pad 57
    int blk = blockIdx.x;              // BB*2*56
    int y = blk % 56, g = (blk/56) & 1, b = blk/112;
    int lane = threadIdx.x;            // 64
    for (int i = lane; i < 32*56; i += 64) {
        int ic = i/56, col = i%56;
        ld[ic*57 + col] = x[((size_t)(b*CC + g*32 + ic))*HWA + y*WW + col];
    }
    __syncthreads();
    _Float16* dst = xh + (((size_t)(b*2+g)*56 + y)*58)*32;
    for (int i = lane; i < 58*32; i += 64) {
        int col = i/32, ic = i%32;
        float v = 0.f;
        if (col >= 1 && col <= 56) v = ld[ic*57 + col - 1];
        dst[i] = (_Float16)v;
    }
}

// ---------- 2b. pack conv weights to A-fragment layout + bias ----------
// Wp[g][kt=ky*3+kx][mt 0..4][lane 0..63][j 0..7] fp16, m = mt*16+(lane&15),
// k-within = (lane>>4)*8+j = ic. m<49: conv3 oc=g*49+m; m<74: conv2 oc=g*25+m-49.
__global__ void k_whpack(const float* __restrict__ w3, const float* __restrict__ w2,
                         const float* __restrict__ b3, const float* __restrict__ b2,
                         _Float16* __restrict__ Wp, float* __restrict__ bbp) {
    int i = blockIdx.x*256 + threadIdx.x;
    if (i < 46080) {
        int j    = i & 7;
        int lane = (i >> 3) & 63;
        int mt   = (i >> 9) % 5;
        int kt   = (i / 2560) % 9;
        int g    = i / 23040;
        int m  = mt*16 + (lane & 15);
        int ic = (lane >> 4)*8 + j;
        int ky = kt/3, kx = kt%3;
        float v = 0.f;
        if (m < 49)      v = w3[((g*49 + m)*32 + ic)*9 + ky*3 + kx];
        else if (m < 74) v = w2[((g*25 + (m-49))*32 + ic)*9 + ky*3 + kx];
        Wp[i] = (_Float16)v;
    } else if (i < 46080 + 160) {
        int t = i - 46080; int g = t/80, m = t%80;
        float v = 0.f;
        if (m < 49)      v = b3[g*49 + m];
        else if (m < 74) v = b2[g*25 + (m-49)];
        bbp[t] = v;
    }
}

// ---------- 3. MFMA conv: both grouped 3x3 convs as one GEMM ----------
// wave = (b, g, row, 16-pixel tile): C[80 oc][16 pix], K = 288 (9 kt x 32 ic)
__global__ __launch_bounds__(64)
void k_convmfma(const _Float16* __restrict__ xh, const _Float16* __restrict__ Wp,
                const float* __restrict__ bb,
                float* __restrict__ off3, float* __restrict__ off2) {
    __shared__ _Float16 tile[3*18*32];  // 1728 halves = 3456 B
    int blk = blockIdx.x;               // ((b*2+g)*56+iy)*4+nq = 1792
    int nq = blk & 3;
    int t  = blk >> 2;
    int iy = t % 56;
    int g  = (t / 56) & 1;
    int b  = t / 112;
    int lane = threadIdx.x;
    int n0 = nq * 16;

    // stage 3 rows x 18 cols x 32 ic fp16 (as uints)
    const unsigned int* xs = (const unsigned int*)xh;
    unsigned int* tl = (unsigned int*)tile;
#pragma unroll
    for (int i = 0; i < 14; ++i) {
        int idx = i*64 + lane;          // 864 uints
        if (idx < 864) {
            int ic2 = idx & 15;
            int seg = idx >> 4;         // 0..53
            int cl = seg % 18, r = seg / 18;
            int y = iy - 1 + r, col = n0 + cl;
            unsigned int v = 0;
            if (y >= 0 && y < 56 && col < 58)
                v = xs[(((size_t)(b*2+g)*56 + y)*58 + col)*16 + ic2];
            tl[idx] = v;
        }
    }
    __syncthreads();

    int nlo = lane & 15, khi = lane >> 4;
    f32x4_t acc[5];
#pragma unroll
    for (int mt = 0; mt < 5; ++mt) acc[mt] = (f32x4_t){0.f,0.f,0.f,0.f};

    const half8_t* wp8 = (const half8_t*)Wp;
#pragma unroll
    for (int kt = 0; kt < 9; ++kt) {
        int ky = kt/3, kx = kt%3;
        half8_t bfrag = *(const half8_t*)&tile[((ky*18) + nlo + kx)*32 + khi*8];
#pragma unroll
        for (int mt = 0; mt < 5; ++mt) {
            half8_t afrag = wp8[(((size_t)g*9 + kt)*5 + mt)*64 + lane];
            acc[mt] = __builtin_amdgcn_mfma_f32_16x16x32_f16(afrag, bfrag, acc[mt], 0, 0, 0);
        }
    }

    // epilogue: D m = (lane>>4)*4 + reg (+16*mt), n = lane&15
    int pixcol = n0 + nlo;
    if (pixcol < 56) {
        int pix = iy*WW + pixcol;
#pragma unroll
        for (int mt = 0; mt < 5; ++mt) {
#pragma unroll
            for (int r = 0; r < 4; ++r) {
                int m = mt*16 + khi*4 + r;
                if (m < 74) {
                    float val = acc[mt][r] + bb[g*80 + m];
                    if (m < 49)
                        off3[((size_t)b*98 + g*49 + m)*HWA + pix] = val;
                    else
                        off2[((size_t)b*50 + g*25 + (m-49))*HWA + pix] = val;
                }
            }
        }
    }
}

// ---------- 4. deformable depthwise conv: fp16-pair src, transposed offsets ----------
template<int K, int KS, int PAD>
__global__ void k_deform(const __half2* __restrict__ xp, const float* __restrict__ offT,
                         const float* __restrict__ wg, const float* __restrict__ bias,
                         float* __restrict__ out) {
    constexpr int R2 = 2*K;
    __shared__ float lw[K*65];          // [t][c] padded
    __shared__ float loff[4*R2];        // [px][2K]
    int tid = threadIdx.x + threadIdx.y*64;   // 256
    int blk = blockIdx.x;               // 3136
    int xcd = blk & 7;                  // slab: (batch, image-half)
    int idx = blk >> 3;
    int b   = xcd >> 1;
    int hw0 = (xcd & 1)*(HWA/2) + idx*4;

    for (int i = tid; i < K*64; i += 256) {
        int c = i / K, t = i % K;
        lw[t*65 + c] = wg[i];
    }
    for (int i = tid; i < 4*R2; i += 256) {
        int p = i / R2, t = i % R2;
        loff[p*R2 + t] = offT[((size_t)b*HWA + hw0 + p)*R2 + t];
    }
    __syncthreads();

    int yp = threadIdx.y;
    int hw = hw0 + yp;
    int h  = hw / WW, w = hw % WW;
    int c  = threadIdx.x;

    const __half2* xb = xp + (size_t)b*HH*57*CC + c;

    float acc = 0.f;
#pragma unroll 2
    for (int t = 0; t < K; ++t) {
        int ky = t / KS, kx = t % KS;
        float oy = loff[yp*R2 + 2*t];       // broadcast LDS
        float ox = loff[yp*R2 + 2*t + 1];
        float py = (float)(h - PAD + 3*ky) + oy;
        float px = (float)(w - PAD + 3*kx) + ox;
        float y0f = floorf(py), x0f = floorf(px);
        float ly = py - y0f, lx = px - x0f;
        float hy = 1.f - ly, hx = 1.f - lx;
        int y0 = (int)y0f, x0 = (int)x0f;
        int j = x0 + 1;                     // pair slot
        float v00 = 0.f, v01 = 0.f, v10 = 0.f, v11 = 0.f;
        if (j >= 0 && j <= 56) {
            if (y0 >= 0 && y0 < HH) {
                float2 r0 = __half22float2(xb[((size_t)y0*57 + j)*CC]);
                v00 = r0.x; v01 = r0.y;
            }
            int y1 = y0 + 1;
            if (y1 >= 0 && y1 < HH) {
                float2 r1 = __half22float2(xb[((size_t)y1*57 + j)*CC]);
                v10 = r1.x; v11 = r1.y;
            }
        }
        acc += (hy*(hx*v00 + lx*v01) + ly*(hx*v10 + lx*v11)) * lw[t*65 + c];
    }
    out[((size_t)b*HWA + hw)*CC + c] = acc + bias[c];
}

// ---------- 5a. GAP stage 1 ----------
__global__ void k_gap1(const float* __restrict__ o1, const float* __restrict__ o2,
                       float* __restrict__ partial) {
    __shared__ float red[4][64];
    int blk   = blockIdx.x;            // BB*2*49
    int chunk = blk % 49;
    int f     = (blk / 49) & 1;
    int b     = blk / 98;
    const float* src = f ? o2 : o1;
    int tid = threadIdx.x;             // 256
    int c = tid & 63, s = tid >> 6;
    int hw0 = chunk * 64;
    float sum = 0.f;
#pragma unroll
    for (int i = 0; i < 16; ++i) {
        int hw = hw0 + s + 4*i;
        sum += src[((size_t)b*HWA + hw)*CC + c];
    }
    red[s][c] = sum;
    __syncthreads();
    if (s == 0)
        partial[((size_t)(b*2 + f)*49 + chunk)*64 + c]
            = red[0][c] + red[1][c] + red[2][c] + red[3][c];
}

// ---------- 5b. GAP stage 2 ----------
__global__ void k_gap2(const float* __restrict__ partial, float* __restrict__ gap) {
    int bf = blockIdx.x;               // 8
    int c  = threadIdx.x;              // 64
    const float* p = partial + (size_t)bf*49*64 + c;
    float tot = 0.f;
    for (int j = 0; j < 49; ++j) tot += p[j*64];
    gap[bf*64 + c] = tot * (1.f/HWA);
}

// ---------- 6. softmax gate + combine, NHWC -> NCHW ----------
__global__ void k_combine(const float* __restrict__ o1, const float* __restrict__ o2,
                          const float* __restrict__ gap, float* __restrict__ out) {
    __shared__ float tile[64][65];
    int blk = blockIdx.x;              // BB * (HWA/64)
    int b   = blk / (HWA/64);
    int t0  = (blk % (HWA/64)) * 64;
    int tid = threadIdx.x;             // 256
    int c = tid & 63, q = tid >> 6;

    float g1 = gap[(b*2+0)*CC + c];
    float g2 = gap[(b*2+1)*CC + c];
    float m  = fmaxf(g1, g2);
    float e1 = expf(g1 - m), e2 = expf(g2 - m);
    float a1 = e1 / (e1 + e2), a2 = 1.f - a1;

#pragma unroll
    for (int i = 0; i < 16; ++i) {
        int p = q + 4*i;
        size_t idx = ((size_t)b*HWA + t0 + p)*CC + c;
        tile[p][c] = o1[idx]*a1 + o2[idx]*a2;
    }
    __syncthreads();
    int p2 = tid & 63;
#pragma unroll
    for (int i = 0; i < 16; ++i) {
        int c2 = q + 4*i;
        out[((size_t)b*CC + c2)*HWA + t0 + p2] = tile[p2][c2];
    }
}

extern "C" void kernel_launch(void* const* d_in, const int* in_sizes, int n_in,
                              void* d_out, int out_size, void* d_ws, size_t ws_size,
                              hipStream_t stream) {
    const float* x      = (const float*)d_in[0];
    const float* w_off3 = (const float*)d_in[1];
    const float* b_off3 = (const float*)d_in[2];
    const float* w_off2 = (const float*)d_in[3];
    const float* b_off2 = (const float*)d_in[4];
    const float* w7     = (const float*)d_in[5];
    const float* b7     = (const float*)d_in[6];
    const float* w5     = (const float*)d_in[7];
    const float* b5     = (const float*)d_in[8];
    float* out = (float*)d_out;

    float* ws    = (float*)d_ws;
    float* off3r = ws;                    // 1229312 (later: xp2 alias)
    float* off2r = off3r + 1229312;       // 627200  (later: gpart alias)
    float* offT3 = off2r + 627200;        // 1229312 (xh aliases its head)
    float* offT2 = offT3 + 1229312;       // 627200
    float* out1  = offT2 + 627200;        // 802816
    float* out2  = out1  + 802816;        // 802816
    float* xp1f  = out2  + 802816;        // 817152 (half2 = 4B units)
    float* gapv  = xp1f  + 817152;        // 512
    float* wpf   = gapv  + 512;           // 23040 (46080 fp16)
    float* bbp   = wpf   + 23040;         // 160
    __half2*  xp1 = (__half2*)xp1f;
    __half2*  xp2 = (__half2*)off3r;      // alias: off3r dead after k_offT
    _Float16* xh  = (_Float16*)offT3;     // alias: xh dead before k_offT writes offT3
    _Float16* Wp  = (_Float16*)wpf;
    float* gpart = off2r;                 // alias: off2r dead after k_offT
    size_t need = (size_t)(1229312 + 627200 + 1229312 + 627200 + 802816*2
                           + 817152 + 512 + 23040 + 160) * 4;
    if (ws_size < need) return;

    k_xh<<<BB*2*56, 64, 0, stream>>>(x, xh);
    k_pairx<<<BB*56, 256, 0, stream>>>(x, xp1);
    k_whpack<<<(46080 + 160 + 255)/256, 256, 0, stream>>>(
        w_off3, w_off2, b_off3, b_off2, Wp, bbp);
    k_convmfma<<<BB*2*56*4, 64, 0, stream>>>(xh, Wp, bbp, off3r, off2r);
    k_offT<<<BB*49, 256, 0, stream>>>(off3r, offT3, 98);
    k_offT<<<BB*49, 256, 0, stream>>>(off2r, offT2, 50);
    k_deform<49,7,9><<<BB*(HWA/4), dim3(64,4), 0, stream>>>(xp1, offT3, w7, b7, out1);
    k_pairo<<<BB*56, 256, 0, stream>>>(out1, xp2);
    k_deform<25,5,6><<<BB*(HWA/4), dim3(64,4), 0, stream>>>(xp2, offT2, w5, b5, out2);
    k_gap1<<<BB*2*49, 256, 0, stream>>>(out1, out2, gpart);
    k_gap2<<<BB*2, 64, 0, stream>>>(gpart, gapv);
    k_combine<<<BB*(HWA/64), 256, 0, stream>>>(out1, out2, gapv, out);
}

// Round 9
// 182.872 us; speedup vs baseline: 34.6957x; 1.2120x over previous
//
#include <hip/hip_runtime.h>
#include <hip/hip_fp16.h>
#include <math.h>

#define HH 56
#define WW 56
#define CC 64
#define BB 4
#define HWA (HH*WW)   // 3136

typedef _Float16 half8_t __attribute__((ext_vector_type(8)));
typedef _Float16 h2_t   __attribute__((ext_vector_type(2)));
typedef float f32x4_t __attribute__((ext_vector_type(4)));

// ---------- 1a. x NCHW -> fp16 x-pair layout xp[b][y][j][c] (deform1 src) ----------
__global__ void k_pairx(const float* __restrict__ x, __half2* __restrict__ xp) {
    __shared__ float ld[64*57];        // [c][xcol] padded stride 57
    int blk = blockIdx.x;              // BB*56
    int b = blk / 56, y = blk % 56;
    int tid = threadIdx.x;             // 256
    for (int i = tid; i < 64*56; i += 256) {
        int c = i / 56, xcol = i % 56;
        ld[c*57 + xcol] = x[((size_t)b*CC + c)*HWA + y*WW + xcol];
    }
    __syncthreads();
    for (int i = tid; i < 57*64; i += 256) {
        int j = i >> 6, c = i & 63;
        float lo = (j > 0)  ? ld[c*57 + j - 1] : 0.f;
        float hi = (j < 56) ? ld[c*57 + j]     : 0.f;
        xp[((size_t)(b*HH + y)*57 + j)*CC + c] = __floats2half2_rn(lo, hi);
    }
}

// ---------- 1b. out1 NHWC fp32 -> fp16 pair layout (deform2 src) ----------
__global__ void k_pairo(const float* __restrict__ o, __half2* __restrict__ xp) {
    __shared__ float ld[56*64];        // [xcol][c]
    int blk = blockIdx.x;              // BB*56
    int b = blk / 56, y = blk % 56;
    int tid = threadIdx.x;             // 256
    for (int i = tid; i < 56*64; i += 256)
        ld[i] = o[((size_t)b*HWA + y*WW)*CC + i];
    __syncthreads();
    for (int i = tid; i < 57*64; i += 256) {
        int j = i >> 6, c = i & 63;
        float lo = (j > 0)  ? ld[(j-1)*64 + c] : 0.f;
        float hi = (j < 56) ? ld[j*64 + c]     : 0.f;
        xp[((size_t)(b*HH + y)*57 + j)*CC + c] = __floats2half2_rn(lo, hi);
    }
}

// ---------- 1c. offsets -> bilinear meta {a0,a1,wA,wB} per (b,hw,tap) ----------
template<int K, int KS, int PAD>
__global__ void k_offmeta(const float* __restrict__ off, int4* __restrict__ meta) {
    constexpr int R = 2*K;
    __shared__ float tile[R*65];
    int blk = blockIdx.x;              // BB*49
    int b = blk / 49;
    int hw0 = (blk % 49) * 64;
    int tid = threadIdx.x;             // 256
    for (int i = tid; i < R*64; i += 256) {
        int row = i >> 6, p = i & 63;
        tile[row*65 + p] = off[((size_t)b*R + row)*HWA + hw0 + p];
    }
    __syncthreads();
    for (int i = tid; i < 64*K; i += 256) {
        int p = i / K, t = i % K;
        int hw = hw0 + p;
        int h = hw / WW, w = hw % WW;
        int ky = t / KS, kx = t % KS;
        float py = (float)(h - PAD + 3*ky) + tile[(2*t)*65 + p];
        float px = (float)(w - PAD + 3*kx) + tile[(2*t+1)*65 + p];
        float y0f = floorf(py), x0f = floorf(px);
        float ly = py - y0f, lx = px - x0f;
        float hy = 1.f - ly, hx = 1.f - lx;
        int y0 = (int)y0f, x0 = (int)x0f;
        int j = x0 + 1;                 // pair slot (handles x edges via zeros)
        bool jv = (j >= 0) && (j <= 56);
        int jc = jv ? j : 0;
        float s0 = ((y0   >= 0) && (y0   < HH) && jv) ? hy : 0.f;
        float s1 = ((y0+1 >= 0) && (y0+1 < HH) && jv) ? ly : 0.f;
        int y0c = min(max(y0,   0), HH-1);
        int y1c = min(max(y0+1, 0), HH-1);
        int4 m;
        m.x = (y0c*57 + jc)*64;
        m.y = (y1c*57 + jc)*64;
        __half2 wa = __floats2half2_rn(s0*hx, s0*lx);
        __half2 wb = __floats2half2_rn(s1*hx, s1*lx);
        m.z = *(int*)&wa;
        m.w = *(int*)&wb;
        meta[((size_t)b*HWA + hw)*K + t] = m;
    }
}

// ---------- 2a. x NCHW -> xh[b][g][y][col 58][ic 32] fp16 (conv B-source) ----------
__global__ void k_xh(const float* __restrict__ x, _Float16* __restrict__ xh) {
    __shared__ float ld[32*57];        // [ic][xcol] pad 57
    int blk = blockIdx.x;              // BB*2*56
    int y = blk % 56, g = (blk/56) & 1, b = blk/112;
    int lane = threadIdx.x;            // 64
    for (int i = lane; i < 32*56; i += 64) {
        int ic = i/56, col = i%56;
        ld[ic*57 + col] = x[((size_t)(b*CC + g*32 + ic))*HWA + y*WW + col];
    }
    __syncthreads();
    _Float16* dst = xh + (((size_t)(b*2+g)*56 + y)*58)*32;
    for (int i = lane; i < 58*32; i += 64) {
        int col = i/32, ic = i%32;
        float v = 0.f;
        if (col >= 1 && col <= 56) v = ld[ic*57 + col - 1];
        dst[i] = (_Float16)v;
    }
}

// ---------- 2b. pack conv weights to A-fragment layout + bias ----------
__global__ void k_whpack(const float* __restrict__ w3, const float* __restrict__ w2,
                         const float* __restrict__ b3, const float* __restrict__ b2,
                         _Float16* __restrict__ Wp, float* __restrict__ bbp) {
    int i = blockIdx.x*256 + threadIdx.x;
    if (i < 46080) {
        int j    = i & 7;
        int lane = (i >> 3) & 63;
        int mt   = (i >> 9) % 5;
        int kt   = (i / 2560) % 9;
        int g    = i / 23040;
        int m  = mt*16 + (lane & 15);
        int ic = (lane >> 4)*8 + j;
        int ky = kt/3, kx = kt%3;
        float v = 0.f;
        if (m < 49)      v = w3[((g*49 + m)*32 + ic)*9 + ky*3 + kx];
        else if (m < 74) v = w2[((g*25 + (m-49))*32 + ic)*9 + ky*3 + kx];
        Wp[i] = (_Float16)v;
    } else if (i < 46080 + 160) {
        int t = i - 46080; int g = t/80, m = t%80;
        float v = 0.f;
        if (m < 49)      v = b3[g*49 + m];
        else if (m < 74) v = b2[g*25 + (m-49)];
        bbp[t] = v;
    }
}

// ---------- 3. MFMA conv: both grouped 3x3 convs as one GEMM ----------
__global__ __launch_bounds__(64)
void k_convmfma(const _Float16* __restrict__ xh, const _Float16* __restrict__ Wp,
                const float* __restrict__ bb,
                float* __restrict__ off3, float* __restrict__ off2) {
    __shared__ _Float16 tile[3*18*32];  // 3456 B
    int blk = blockIdx.x;               // 1792
    int nq = blk & 3;
    int t  = blk >> 2;
    int iy = t % 56;
    int g  = (t / 56) & 1;
    int b  = t / 112;
    int lane = threadIdx.x;
    int n0 = nq * 16;

    const unsigned int* xs = (const unsigned int*)xh;
    unsigned int* tl = (unsigned int*)tile;
#pragma unroll
    for (int i = 0; i < 14; ++i) {
        int idx = i*64 + lane;          // 864 uints
        if (idx < 864) {
            int ic2 = idx & 15;
            int seg = idx >> 4;
            int cl = seg % 18, r = seg / 18;
            int y = iy - 1 + r, col = n0 + cl;
            unsigned int v = 0;
            if (y >= 0 && y < 56 && col < 58)
                v = xs[(((size_t)(b*2+g)*56 + y)*58 + col)*16 + ic2];
            tl[idx] = v;
        }
    }
    __syncthreads();

    int nlo = lane & 15, khi = lane >> 4;
    f32x4_t acc[5];
#pragma unroll
    for (int mt = 0; mt < 5; ++mt) acc[mt] = (f32x4_t){0.f,0.f,0.f,0.f};

    const half8_t* wp8 = (const half8_t*)Wp;
#pragma unroll
    for (int kt = 0; kt < 9; ++kt) {
        int ky = kt/3, kx = kt%3;
        half8_t bfrag = *(const half8_t*)&tile[((ky*18) + nlo + kx)*32 + khi*8];
#pragma unroll
        for (int mt = 0; mt < 5; ++mt) {
            half8_t afrag = wp8[(((size_t)g*9 + kt)*5 + mt)*64 + lane];
            acc[mt] = __builtin_amdgcn_mfma_f32_16x16x32_f16(afrag, bfrag, acc[mt], 0, 0, 0);
        }
    }

    int pixcol = n0 + nlo;
    if (pixcol < 56) {
        int pix = iy*WW + pixcol;
#pragma unroll
        for (int mt = 0; mt < 5; ++mt) {
#pragma unroll
            for (int r = 0; r < 4; ++r) {
                int m = mt*16 + khi*4 + r;
                if (m < 74) {
                    float val = acc[mt][r] + bb[g*80 + m];
                    if (m < 49)
                        off3[((size_t)b*98 + g*49 + m)*HWA + pix] = val;
                    else
                        off2[((size_t)b*50 + g*25 + (m-49))*HWA + pix] = val;
                }
            }
        }
    }
}

// ---------- 4. deformable depthwise conv: meta-driven gather + fdot2 ----------
template<int K>
__global__ void k_deform(const h2_t* __restrict__ xp, const int4* __restrict__ meta,
                         const float* __restrict__ wg, const float* __restrict__ bias,
                         float* __restrict__ out) {
    __shared__ float lw[K*65];          // [t][c] padded
    __shared__ int4 lmeta[4*K];         // [px][K]
    int tid = threadIdx.x + threadIdx.y*64;   // 256
    int blk = blockIdx.x;               // 3136
    int xcd = blk & 7;                  // slab: (batch, image-half)
    int idx = blk >> 3;
    int b   = xcd >> 1;
    int hw0 = (xcd & 1)*(HWA/2) + idx*4;

    for (int i = tid; i < K*64; i += 256) {
        int c = i / K, t = i % K;
        lw[t*65 + c] = wg[i];
    }
    for (int i = tid; i < 4*K; i += 256)
        lmeta[i] = meta[((size_t)b*HWA + hw0)*K + i];
    __syncthreads();

    int yp = threadIdx.y;
    int c  = threadIdx.x;
    const h2_t* xb = xp + (size_t)b*HH*57*CC + c;

    float acc = 0.f;
#pragma unroll 2
    for (int t = 0; t < K; ++t) {
        int4 m = lmeta[yp*K + t];
        h2_t r0 = xb[m.x];
        h2_t r1 = xb[m.y];
        h2_t wA = *(h2_t*)&m.z;
        h2_t wB = *(h2_t*)&m.w;
        float v = __builtin_amdgcn_fdot2(r0, wA, 0.f, false);
        v = __builtin_amdgcn_fdot2(r1, wB, v, false);
        acc = fmaf(v, lw[t*65 + c], acc);
    }
    out[((size_t)b*HWA + hw0 + yp)*CC + c] = acc + bias[c];
}

// ---------- 5a. GAP stage 1 ----------
__global__ void k_gap1(const float* __restrict__ o1, const float* __restrict__ o2,
                       float* __restrict__ partial) {
    __shared__ float red[4][64];
    int blk   = blockIdx.x;            // BB*2*49
    int chunk = blk % 49;
    int f     = (blk / 49) & 1;
    int b     = blk / 98;
    const float* src = f ? o2 : o1;
    int tid = threadIdx.x;             // 256
    int c = tid & 63, s = tid >> 6;
    int hw0 = chunk * 64;
    float sum = 0.f;
#pragma unroll
    for (int i = 0; i < 16; ++i) {
        int hw = hw0 + s + 4*i;
        sum += src[((size_t)b*HWA + hw)*CC + c];
    }
    red[s][c] = sum;
    __syncthreads();
    if (s == 0)
        partial[((size_t)(b*2 + f)*49 + chunk)*64 + c]
            = red[0][c] + red[1][c] + red[2][c] + red[3][c];
}

// ---------- 5b. GAP stage 2 ----------
__global__ void k_gap2(const float* __restrict__ partial, float* __restrict__ gap) {
    int bf = blockIdx.x;               // 8
    int c  = threadIdx.x;              // 64
    const float* p = partial + (size_t)bf*49*64 + c;
    float tot = 0.f;
    for (int j = 0; j < 49; ++j) tot += p[j*64];
    gap[bf*64 + c] = tot * (1.f/HWA);
}

// ---------- 6. softmax gate + combine, NHWC -> NCHW ----------
__global__ void k_combine(const float* __restrict__ o1, const float* __restrict__ o2,
                          const float* __restrict__ gap, float* __restrict__ out) {
    __shared__ float tile[64][65];
    int blk = blockIdx.x;              // BB * (HWA/64)
    int b   = blk / (HWA/64);
    int t0  = (blk % (HWA/64)) * 64;
    int tid = threadIdx.x;             // 256
    int c = tid & 63, q = tid >> 6;

    float g1 = gap[(b*2+0)*CC + c];
    float g2 = gap[(b*2+1)*CC + c];
    float m  = fmaxf(g1, g2);
    float e1 = expf(g1 - m), e2 = expf(g2 - m);
    float a1 = e1 / (e1 + e2), a2 = 1.f - a1;

#pragma unroll
    for (int i = 0; i < 16; ++i) {
        int p = q + 4*i;
        size_t idx = ((size_t)b*HWA + t0 + p)*CC + c;
        tile[p][c] = o1[idx]*a1 + o2[idx]*a2;
    }
    __syncthreads();
    int p2 = tid & 63;
#pragma unroll
    for (int i = 0; i < 16; ++i) {
        int c2 = q + 4*i;
        out[((size_t)b*CC + c2)*HWA + t0 + p2] = tile[p2][c2];
    }
}

extern "C" void kernel_launch(void* const* d_in, const int* in_sizes, int n_in,
                              void* d_out, int out_size, void* d_ws, size_t ws_size,
                              hipStream_t stream) {
    const float* x      = (const float*)d_in[0];
    const float* w_off3 = (const float*)d_in[1];
    const float* b_off3 = (const float*)d_in[2];
    const float* w_off2 = (const float*)d_in[3];
    const float* b_off2 = (const float*)d_in[4];
    const float* w7     = (const float*)d_in[5];
    const float* b7     = (const float*)d_in[6];
    const float* w5     = (const float*)d_in[7];
    const float* b5     = (const float*)d_in[8];
    float* out = (float*)d_out;

    float* ws    = (float*)d_ws;
    float* off3r = ws;                    // 1229312 (later: xp2 alias)
    float* off2r = off3r + 1229312;       // 627200  (later: gpart alias)
    float* meta1f= off2r + 627200;        // 2458624 (int4 x 614656); head aliased by xh
    float* meta2f= meta1f+ 2458624;       // 1254400 (int4 x 313600)
    float* out1  = meta2f+ 1254400;       // 802816
    float* out2  = out1  + 802816;        // 802816
    float* xp1f  = out2  + 802816;        // 817152 (half2 = 4B units)
    float* gapv  = xp1f  + 817152;        // 512
    float* wpf   = gapv  + 512;           // 23040 (46080 fp16)
    float* bbp   = wpf   + 23040;         // 160
    __half2*  xp1 = (__half2*)xp1f;
    __half2*  xp2 = (__half2*)off3r;      // alias: off3r dead after k_offmeta
    _Float16* xh  = (_Float16*)meta1f;    // alias: xh dead before k_offmeta writes meta1
    _Float16* Wp  = (_Float16*)wpf;
    int4* meta1 = (int4*)meta1f;
    int4* meta2 = (int4*)meta2f;
    float* gpart = off2r;                 // alias: off2r dead after k_offmeta
    size_t need = (size_t)(1229312 + 627200 + 2458624 + 1254400 + 802816*2
                           + 817152 + 512 + 23040 + 160) * 4;
    if (ws_size < need) return;

    k_xh<<<BB*2*56, 64, 0, stream>>>(x, xh);
    k_pairx<<<BB*56, 256, 0, stream>>>(x, xp1);
    k_whpack<<<(46080 + 160 + 255)/256, 256, 0, stream>>>(
        w_off3, w_off2, b_off3, b_off2, Wp, bbp);
    k_convmfma<<<BB*2*56*4, 64, 0, stream>>>(xh, Wp, bbp, off3r, off2r);
    k_offmeta<49,7,9><<<BB*49, 256, 0, stream>>>(off3r, meta1);
    k_offmeta<25,5,6><<<BB*49, 256, 0, stream>>>(off2r, meta2);
    k_deform<49><<<BB*(HWA/4), dim3(64,4), 0, stream>>>((const h2_t*)xp1, meta1, w7, b7, out1);
    k_pairo<<<BB*56, 256, 0, stream>>>(out1, xp2);
    k_deform<25><<<BB*(HWA/4), dim3(64,4), 0, stream>>>((const h2_t*)xp2, meta2, w5, b5, out2);
    k_gap1<<<BB*2*49, 256, 0, stream>>>(out1, out2, gpart);
    k_gap2<<<BB*2, 64, 0, stream>>>(gpart, gapv);
    k_combine<<<BB*(HWA/64), 256, 0, stream>>>(out1, out2, gapv, out);
}